// Round 3
// baseline (1422.252 us; speedup 1.0000x reference)
//
#include <hip/hip_runtime.h>
#include <stdint.h>

// ---------- types ----------
typedef unsigned short u16;
typedef u16   u16x4 __attribute__((ext_vector_type(4)));
typedef u16   u16x8 __attribute__((ext_vector_type(8)));
typedef float f32x4 __attribute__((ext_vector_type(4)));
typedef __bf16 bf16x8 __attribute__((ext_vector_type(8)));

// ---------- constants ----------
#define BB    16
#define NN    3136
#define CC    576
#define HEADS 8
#define HD    72
#define AGN   49
#define NTOT  1728
#define NCH   16                     // stageA chunks
#define SCALE 0.1178511301977579f   // 72^-0.5

__device__ __forceinline__ u16 f2bf(float f) {
    unsigned u = __float_as_uint(f);
    return (u16)((u + 0x7fffu + ((u >> 16) & 1u)) >> 16);
}
__device__ __forceinline__ float bf2f(u16 u) {
    return __uint_as_float(((unsigned)u) << 16);
}

// ---------- cast x -> bf16 ----------
__global__ __launch_bounds__(256) void k_cast_x(const float* __restrict__ x, u16* __restrict__ xb) {
    size_t i = (size_t)blockIdx.x * 256 + threadIdx.x;
    f32x4 v = *(const f32x4*)(x + i * 4);
    u16x4 o; o[0] = f2bf(v[0]); o[1] = f2bf(v[1]); o[2] = f2bf(v[2]); o[3] = f2bf(v[3]);
    *(u16x4*)(xb + i * 4) = o;
}

// ---------- pack transposed bf16 weights ----------
__global__ __launch_bounds__(256) void k_prep_w(const float* __restrict__ Wq, const float* __restrict__ Wkv,
                                                const float* __restrict__ Wp,
                                                u16* __restrict__ wbT, u16* __restrict__ wpT) {
    int idx = blockIdx.x * 256 + threadIdx.x;
    if (idx < NTOT * CC) {
        int nn = idx / CC, kk = idx % CC;
        float v = (nn < CC) ? Wq[kk * CC + nn] : Wkv[kk * (2 * CC) + (nn - CC)];
        wbT[idx] = f2bf(v);
    } else {
        int j = idx - NTOT * CC;
        int nn = j / CC, kk = j % CC;
        wpT[j] = f2bf(Wp[kk * CC + nn]);
    }
}

// ---------- jax.image.resize 'linear' 7x7 -> 56x56 ----------
__device__ __forceinline__ float bilerp7(const float* __restrict__ g, int oy, int ox) {
    float cy = (oy - 3.5f) * 0.125f;
    float cx = (ox - 3.5f) * 0.125f;
    float fy0 = floorf(cy), fx0 = floorf(cx);
    float ty = cy - fy0, tx = cx - fx0;
    int iy0 = (int)fy0, ix0 = (int)fx0;
    int y0 = min(6, max(0, iy0)), y1 = min(6, max(0, iy0 + 1));
    int x0 = min(6, max(0, ix0)), x1 = min(6, max(0, ix0 + 1));
    float g00 = g[y0 * 7 + x0], g01 = g[y0 * 7 + x1];
    float g10 = g[y1 * 7 + x0], g11 = g[y1 * 7 + x1];
    return (1.f - ty) * ((1.f - tx) * g00 + tx * g01) + ty * ((1.f - tx) * g10 + tx * g11);
}

__global__ __launch_bounds__(256) void k_bias1(const float* __restrict__ an, const float* __restrict__ ah,
                                               const float* __restrict__ aw, float* __restrict__ b1) {
    int idx = blockIdx.x * 256 + threadIdx.x;
    int n = idx % NN; int r = idx / NN; int ag = r % AGN; int h = r / AGN;
    int y = n / 56, x = n % 56;
    float v = bilerp7(an + (h * AGN + ag) * 49, y, x);
    b1[idx] = v + ah[(h * AGN + ag) * 56 + y] + aw[(h * AGN + ag) * 56 + x];
}

__global__ __launch_bounds__(256) void k_bias2(const float* __restrict__ na, const float* __restrict__ ha,
                                               const float* __restrict__ wa, float* __restrict__ b2) {
    int idx = blockIdx.x * 256 + threadIdx.x;
    int ag = idx % AGN; int r = idx / AGN; int n = r % NN; int h = r / NN;
    int y = n / 56, x = n % 56;
    float v = bilerp7(na + (h * AGN + ag) * 49, y, x);
    b2[idx] = v + ha[(h * 56 + y) * AGN + ag] + wa[(h * 56 + x) * AGN + ag];
}

// ---------- MFMA GEMM: A[M x 576] @ Bt[N x 576]^T,  BM=128 BN=64 BK=64 ----------
template<int MODE>
__global__ __launch_bounds__(256) void k_gemm(const u16* __restrict__ A, const u16* __restrict__ Bt,
                                              u16* __restrict__ Qp, u16* __restrict__ Kp, u16* __restrict__ Vp,
                                              float* __restrict__ Cf, const float* __restrict__ bias) {
    __shared__ u16 Asm[128 * 64];
    __shared__ u16 Bsm[64 * 64];
    const int t = threadIdx.x, lane = t & 63, wid = t >> 6;
    const int wm = wid & 1, wn = wid >> 1;
    const int row0 = blockIdx.y * 128, col0 = blockIdx.x * 64;
    const int lr = lane & 15, lk = lane >> 4;
    f32x4 acc[4][2];
#pragma unroll
    for (int m = 0; m < 4; m++)
#pragma unroll
        for (int n2 = 0; n2 < 2; n2++) acc[m][n2] = (f32x4)0.f;

    for (int kt = 0; kt < 9; ++kt) {
        const int k0 = kt * 64;
#pragma unroll
        for (int it = 0; it < 4; ++it) {
            int flat = it * 256 + wid * 64 + lane;
            int r = flat >> 3, lc = (flat & 7) ^ (r & 7);
            const u16* src = A + (size_t)(row0 + r) * CC + k0 + lc * 8;
            __builtin_amdgcn_global_load_lds((const __attribute__((address_space(1))) void*)src,
                                             (__attribute__((address_space(3))) void*)(&Asm[(it * 256 + wid * 64) * 8]),
                                             16, 0, 0);
        }
#pragma unroll
        for (int it = 0; it < 2; ++it) {
            int flat = it * 256 + wid * 64 + lane;
            int r = flat >> 3, lc = (flat & 7) ^ (r & 7);
            const u16* src = Bt + (size_t)(col0 + r) * CC + k0 + lc * 8;
            __builtin_amdgcn_global_load_lds((const __attribute__((address_space(1))) void*)src,
                                             (__attribute__((address_space(3))) void*)(&Bsm[(it * 256 + wid * 64) * 8]),
                                             16, 0, 0);
        }
        __syncthreads();
#pragma unroll
        for (int kk = 0; kk < 2; ++kk) {
            const int klocal2 = (kk * 32 + lk * 8) * 2;
            bf16x8 av[4], bv[2];
#pragma unroll
            for (int m = 0; m < 4; m++) {
                int row = wm * 64 + m * 16 + lr;
                av[m] = *(const bf16x8*)((const char*)Asm + row * 128 + (klocal2 ^ ((row & 7) << 4)));
            }
#pragma unroll
            for (int n2 = 0; n2 < 2; n2++) {
                int row = wn * 32 + n2 * 16 + lr;
                bv[n2] = *(const bf16x8*)((const char*)Bsm + row * 128 + (klocal2 ^ ((row & 7) << 4)));
            }
#pragma unroll
            for (int m = 0; m < 4; m++)
#pragma unroll
                for (int n2 = 0; n2 < 2; n2++)
                    acc[m][n2] = __builtin_amdgcn_mfma_f32_16x16x32_bf16(av[m], bv[n2], acc[m][n2], 0, 0, 0);
        }
        __syncthreads();
    }
#pragma unroll
    for (int n2 = 0; n2 < 2; n2++) {
        int cgl = col0 + wn * 32 + n2 * 16 + lr;
        if (MODE == 0) {
            int which = cgl / 576;
            int rem = cgl - which * 576;
            int hh = rem / 72;
            int dd = rem - hh * 72;
            u16* dst = which == 0 ? Qp : (which == 1 ? Kp : Vp);
#pragma unroll
            for (int m = 0; m < 4; m++)
#pragma unroll
                for (int j = 0; j < 4; j++) {
                    int rgl = row0 + wm * 64 + m * 16 + lk * 4 + j;
                    int b = rgl / NN, n = rgl - b * NN;
                    dst[((size_t)(b * 8 + hh) * NN + n) * 72 + dd] = f2bf(acc[m][n2][j]);
                }
        } else {
#pragma unroll
            for (int m = 0; m < 4; m++)
#pragma unroll
                for (int j = 0; j < 4; j++) {
                    int rgl = row0 + wm * 64 + m * 16 + lk * 4 + j;
                    Cf[(size_t)rgl * 576 + cgl] = acc[m][n2][j] + bias[cgl];
                }
        }
    }
}

// ---------- agent pooling (head-planar q): a[b][ag][c] ----------
__global__ __launch_bounds__(256) void k_pool(const u16* __restrict__ Qp, float* __restrict__ a_f) {
    int idx = blockIdx.x * 256 + threadIdx.x;
    int c = idx % CC; int r = idx / CC; int ag = r % AGN; int b = r / AGN;
    int hh = c / 72, dd = c - hh * 72;
    int p1 = ag / 7, p2 = ag % 7;
    const u16* base = Qp + ((size_t)(b * 8 + hh) * NN) * 72 + dd;
    float s = 0.f;
    for (int i = 0; i < 8; i++)
        for (int j = 0; j < 8; j++)
            s += bf2f(base[(size_t)((p1 * 8 + i) * 56 + p2 * 8 + j) * 72]);
    a_f[idx] = s * 0.015625f;
}

// ---------- stage A: flash over n; batched shuffle reductions, reg-resident m/l ----------
__global__ __launch_bounds__(256) void k_stageA(const u16* __restrict__ Kp, const u16* __restrict__ Vp,
                                                const float* __restrict__ a_f, const float* __restrict__ bias1,
                                                float* __restrict__ part) {
    const int t = threadIdx.x, lane = t & 63, w = t >> 6;
    const int bh = blockIdx.y, b = bh >> 3, h = bh & 7;
    const int chunk = blockIdx.x;                        // 0..15
    const int t0 = chunk * 3;
    const int ntile = (chunk == NCH - 1) ? 4 : 3;

    __shared__ float a_s[49][72];                        // 14112 B
    __shared__ u16   kfb[64][80];                        // 10240 B (16B-aligned rows)
    __shared__ u16   vfs[64][80];                        // 10240 B
    __shared__ float sc[49][64];                         // 12544 B
    __shared__ float rs_s[49];                           //   196 B

    for (int idx = t; idx < 49 * 72; idx += 256) {
        int r = idx / 72, dd = idx - r * 72;
        a_s[r][dd] = a_f[(size_t)(b * 49 + r) * CC + h * 72 + dd] * SCALE;
    }
    // wave-owned rows: row(q) = 16*(q>>2) + 4*w + (q&3)
    int rowc[16];
#pragma unroll
    for (int q = 0; q < 16; q++) {
        int row = 16 * (q >> 2) + 4 * w + (q & 3);
        rowc[q] = min(row, 48);
    }
    float m_run[16], l_run[16];
#pragma unroll
    for (int q = 0; q < 16; q++) { m_run[q] = -1e30f; l_run[q] = 0.f; }
    float acc[4][4];
#pragma unroll
    for (int p = 0; p < 4; p++)
#pragma unroll
        for (int r = 0; r < 4; r++) acc[p][r] = 0.f;
    __syncthreads();

    const size_t kvbase = ((size_t)(b * 8 + h) * NN + t0 * 64) * 72;
    for (int tile = 0; tile < ntile; ++tile) {
        const int n0 = (t0 + tile) * 64;
        const u16* kb = Kp + kvbase + (size_t)tile * 64 * 72;
        const u16* vb = Vp + kvbase + (size_t)tile * 64 * 72;
        // stage K,V tiles (bf16, stride-80 rows)
        for (int idx = t; idx < 576; idx += 256) {
            int nl = idx / 9, ch = idx - nl * 9;
            u16x8 kd = *(const u16x8*)(kb + idx * 8);
            u16x8 vd = *(const u16x8*)(vb + idx * 8);
            *(u16x8*)&kfb[nl][ch * 8] = kd;
            *(u16x8*)&vfs[nl][ch * 8] = vd;
        }
        __syncthreads();
        // ---- scores: sv[16] = bias + a . k(lane) ----
        float sv[16];
#pragma unroll
        for (int q = 0; q < 16; q++)
            sv[q] = bias1[(size_t)(h * 49 + rowc[q]) * NN + n0 + lane];
#pragma unroll
        for (int dq = 0; dq < 9; ++dq) {
            u16x8 k8 = *(const u16x8*)&kfb[lane][dq * 8];
            float kf0 = bf2f(k8[0]), kf1 = bf2f(k8[1]), kf2 = bf2f(k8[2]), kf3 = bf2f(k8[3]);
            float kf4 = bf2f(k8[4]), kf5 = bf2f(k8[5]), kf6 = bf2f(k8[6]), kf7 = bf2f(k8[7]);
#pragma unroll
            for (int q = 0; q < 16; q++) {
                const float* ap = &a_s[rowc[q]][dq * 8];
                f32x4 a0 = *(const f32x4*)ap;
                f32x4 a1 = *(const f32x4*)(ap + 4);
                sv[q] += kf0 * a0[0] + kf1 * a0[1] + kf2 * a0[2] + kf3 * a0[3]
                       + kf4 * a1[0] + kf5 * a1[1] + kf6 * a1[2] + kf7 * a1[3];
            }
        }
        // ---- batched max reduction (16 independent chains) ----
        float mt[16];
#pragma unroll
        for (int q = 0; q < 16; q++) mt[q] = sv[q];
#pragma unroll
        for (int s = 1; s <= 32; s <<= 1) {
#pragma unroll
            for (int q = 0; q < 16; q++) mt[q] = fmaxf(mt[q], __shfl_xor(mt[q], s, 64));
        }
        float ps[16];
#pragma unroll
        for (int q = 0; q < 16; q++) {
            float mnew = fmaxf(m_run[q], mt[q]);
            float p = __expf(sv[q] - mnew);
            mt[q] = mnew;                                // reuse mt as mnew
            ps[q] = p;
            int row = 16 * (q >> 2) + 4 * w + (q & 3);
            if (row < 49) sc[row][lane] = p;
        }
#pragma unroll
        for (int s = 1; s <= 32; s <<= 1) {
#pragma unroll
            for (int q = 0; q < 16; q++) ps[q] += __shfl_xor(ps[q], s, 64);
        }
#pragma unroll
        for (int q = 0; q < 16; q++) {
            float rsc = __expf(m_run[q] - mt[q]);
            l_run[q] = l_run[q] * rsc + ps[q];
            m_run[q] = mt[q];
            int row = 16 * (q >> 2) + 4 * w + (q & 3);
            if (lane == 0 && row < 49) rs_s[row] = rsc;
        }
        __syncthreads();
        // ---- PV: thread owns (rowgrp-of-4, d) ----
#pragma unroll
        for (int p = 0; p < 4; p++) {
            int idx = t + p * 256;
            if (idx < 936) {
                int rg = idx / 72, d = idx - rg * 72;
                int rb2 = rg * 4;
                int rcl[4]; float ar[4];
#pragma unroll
                for (int r = 0; r < 4; r++) { rcl[r] = min(rb2 + r, 48); ar[r] = acc[p][r] * rs_s[rcl[r]]; }
                for (int cq = 0; cq < 16; ++cq) {
                    f32x4 s4[4];
#pragma unroll
                    for (int r = 0; r < 4; r++) s4[r] = *(const f32x4*)&sc[rcl[r]][cq * 4];
#pragma unroll
                    for (int j = 0; j < 4; j++) {
                        float vv = bf2f(vfs[cq * 4 + j][d]);
#pragma unroll
                        for (int r = 0; r < 4; r++) ar[r] += s4[r][j] * vv;
                    }
                }
#pragma unroll
                for (int r = 0; r < 4; r++) acc[p][r] = ar[r];
            }
        }
        __syncthreads();
    }
    // ---- write partials: AV from PV threads, (m,l) from score-owning waves ----
    const size_t pbase = (size_t)(bh * NCH + chunk) * (49 * 74);
#pragma unroll
    for (int p = 0; p < 4; p++) {
        int idx = t + p * 256;
        if (idx < 936) {
            int rg = idx / 72, d = idx - rg * 72;
#pragma unroll
            for (int r = 0; r < 4; r++) {
                int row = rg * 4 + r;
                if (row < 49) part[pbase + row * 74 + d] = acc[p][r];
            }
        }
    }
    if (lane == 0) {
#pragma unroll
        for (int q = 0; q < 16; q++) {
            int row = 16 * (q >> 2) + 4 * w + (q & 3);
            if (row < 49) {
                part[pbase + row * 74 + 72] = m_run[q];
                part[pbase + row * 74 + 73] = l_run[q];
            }
        }
    }
}

// ---------- reduce partials across NCH chunks ----------
__global__ __launch_bounds__(256) void k_reduceA(const float* __restrict__ part, float* __restrict__ agv) {
    const int bh = blockIdx.x, t = threadIdx.x;
    const float* pb = part + (size_t)bh * NCH * (49 * 74);
    for (int idx = t; idx < 49 * 72; idx += 256) {
        int row = idx / 72, d = idx - row * 72;
        float m = -1e30f;
#pragma unroll
        for (int c = 0; c < NCH; c++) m = fmaxf(m, pb[c * (49 * 74) + row * 74 + 72]);
        float accv = 0.f, l = 0.f;
#pragma unroll
        for (int c = 0; c < NCH; c++) {
            const float* pc = pb + c * (49 * 74) + row * 74;
            float e = __expf(pc[72] - m);
            accv += pc[d] * e;
            l += pc[73] * e;
        }
        agv[(size_t)(bh * 49 + row) * 72 + d] = accv / l;
    }
}

// ---------- stage B: per-token softmax over 49 agents + PV ----------
__global__ __launch_bounds__(256) void k_stageB(const u16* __restrict__ Qp, const float* __restrict__ a_f,
                                                const float* __restrict__ agent_v, const float* __restrict__ bias2,
                                                float* __restrict__ outatt) {
    const int t = threadIdx.x;
    const int bh = blockIdx.y; const int b = bh >> 3, h = bh & 7;
    __shared__ float a_s[49][72];
    __shared__ float av[49][72];
    for (int idx = t; idx < 49 * 72; idx += 256) {
        int ag = idx / 72, dd = idx % 72;
        a_s[ag][dd] = a_f[(size_t)(b * AGN + ag) * CC + h * HD + dd] * SCALE;
        av[ag][dd]  = agent_v[(size_t)(bh * AGN + ag) * HD + dd];
    }
    __syncthreads();
    const int n = blockIdx.x * 256 + t;
    if (n >= NN) return;
    const u16* qp = Qp + ((size_t)(b * 8 + h) * NN + n) * 72;
    const float* brow = bias2 + ((size_t)h * NN + n) * AGN;
    float s[49];
#pragma unroll
    for (int ag = 0; ag < 49; ++ag) s[ag] = brow[ag];
    for (int ch = 0; ch < 9; ++ch) {
        u16x8 qc = *(const u16x8*)(qp + ch * 8);
        float qf[8];
#pragma unroll
        for (int j = 0; j < 8; j++) qf[j] = bf2f(qc[j]);
#pragma unroll
        for (int ag = 0; ag < 49; ++ag) {
            float a2 = s[ag];
#pragma unroll
            for (int j = 0; j < 8; j++) a2 += qf[j] * a_s[ag][ch * 8 + j];
            s[ag] = a2;
        }
    }
    float mx = -1e30f;
#pragma unroll
    for (int ag = 0; ag < 49; ++ag) mx = fmaxf(mx, s[ag]);
    float l = 0.f;
#pragma unroll
    for (int ag = 0; ag < 49; ++ag) { float p = __expf(s[ag] - mx); s[ag] = p; l += p; }
    float inv = 1.f / l;
#pragma unroll
    for (int ag = 0; ag < 49; ++ag) s[ag] *= inv;
    float* op = outatt + (size_t)(b * NN + n) * CC + h * HD;
    for (int dc = 0; dc < 9; ++dc) {
        float o8[8] = {0.f, 0.f, 0.f, 0.f, 0.f, 0.f, 0.f, 0.f};
#pragma unroll
        for (int ag = 0; ag < 49; ++ag)
#pragma unroll
            for (int j = 0; j < 8; j++) o8[j] += s[ag] * av[ag][dc * 8 + j];
#pragma unroll
        for (int j = 0; j < 8; j++) op[dc * 8 + j] = o8[j];
    }
}

// ---------- depthwise 3x3 conv + affine + relu + add, emit bf16 'pre' ----------
__global__ __launch_bounds__(256) void k_conv(const u16* __restrict__ Vp, const float* __restrict__ outatt,
                                              const float* __restrict__ w, const float* __restrict__ gamma,
                                              const float* __restrict__ beta, u16* __restrict__ pre) {
    int idx = blockIdx.x * 256 + threadIdx.x;
    int c4 = idx % 144; int rest = idx / 144; int n = rest % NN; int b = rest / NN;
    int y = n / 56, x = n % 56;
    int c0 = c4 * 4;
    int hh = c0 / 72, dl = c0 - hh * 72;
    const u16* vbase = Vp + ((size_t)(b * 8 + hh) * NN) * 72 + dl;
    float a0 = 0.f, a1 = 0.f, a2 = 0.f, a3 = 0.f;
#pragma unroll
    for (int dy = -1; dy <= 1; ++dy) {
        int yy = y + dy; if (yy < 0 || yy > 55) continue;
#pragma unroll
        for (int dx = -1; dx <= 1; ++dx) {
            int xx = x + dx; if (xx < 0 || xx > 55) continue;
            u16x4 vv = *(const u16x4*)(vbase + (size_t)(yy * 56 + xx) * 72);
            int tap = (dy + 1) * 3 + (dx + 1);
            a0 += bf2f(vv[0]) * w[(c0 + 0) * 9 + tap];
            a1 += bf2f(vv[1]) * w[(c0 + 1) * 9 + tap];
            a2 += bf2f(vv[2]) * w[(c0 + 2) * 9 + tap];
            a3 += bf2f(vv[3]) * w[(c0 + 3) * 9 + tap];
        }
    }
    const float* oa = outatt + (size_t)(b * NN + n) * CC + c0;
    f32x4 o = *(const f32x4*)oa;
    float y0 = fmaxf(a0 * gamma[c0 + 0] + beta[c0 + 0], 0.f);
    float y1 = fmaxf(a1 * gamma[c0 + 1] + beta[c0 + 1], 0.f);
    float y2 = fmaxf(a2 * gamma[c0 + 2] + beta[c0 + 2], 0.f);
    float y3 = fmaxf(a3 * gamma[c0 + 3] + beta[c0 + 3], 0.f);
    u16x4 rr; rr[0] = f2bf(o[0] + y0); rr[1] = f2bf(o[1] + y1); rr[2] = f2bf(o[2] + y2); rr[3] = f2bf(o[3] + y3);
    *(u16x4*)(pre + (size_t)(b * NN + n) * CC + c0) = rr;
}

// ---------- launch ----------
extern "C" void kernel_launch(void* const* d_in, const int* in_sizes, int n_in,
                              void* d_out, int out_size, void* d_ws, size_t ws_size,
                              hipStream_t stream) {
    const float* x     = (const float*)d_in[0];
    const float* Wq    = (const float*)d_in[1];
    const float* Wkv   = (const float*)d_in[2];
    const float* an_b  = (const float*)d_in[3];
    const float* na_b  = (const float*)d_in[4];
    const float* ah_b  = (const float*)d_in[5];
    const float* aw_b  = (const float*)d_in[6];
    const float* ha_b  = (const float*)d_in[7];
    const float* wa_b  = (const float*)d_in[8];
    const float* dwcw  = (const float*)d_in[9];
    const float* gam   = (const float*)d_in[10];
    const float* bet   = (const float*)d_in[11];
    const float* projw = (const float*)d_in[12];
    const float* projb = (const float*)d_in[13];
    float* out = (float*)d_out;

    char* ws = (char*)d_ws;
    u16* wbT  = (u16*)(ws + 0);                          //  1,990,656
    u16* wpT  = (u16*)(ws + 1990656);                    //    663,552
    u16* xb   = (u16*)(ws + 2654208);                    // 57,802,752 (reused: stageA partials, then 'pre')
    u16* Qp   = (u16*)(ws + 60456960);                   // 57,802,752
    u16* Kp   = (u16*)(ws + 118259712);                  // 57,802,752
    u16* Vp   = (u16*)(ws + 176062464);                  // 57,802,752
    float* af = (float*)(ws + 233865216);                //  1,806,336
    float* agv= (float*)(ws + 235671552);                //  1,806,336
    float* b1 = (float*)(ws + 237477888);                //  4,917,248
    float* b2 = (float*)(ws + 242395136);                //  4,917,248
    float* part = (float*)xb;                            // 29,700,608 (inside xb region)

    k_cast_x<<<28224, 256, 0, stream>>>(x, xb);
    k_prep_w<<<5184, 256, 0, stream>>>(Wq, Wkv, projw, wbT, wpT);
    k_bias1<<<4802, 256, 0, stream>>>(an_b, ah_b, aw_b, b1);
    k_bias2<<<4802, 256, 0, stream>>>(na_b, ha_b, wa_b, b2);
    k_gemm<0><<<dim3(27, 392), 256, 0, stream>>>(xb, wbT, Qp, Kp, Vp, nullptr, nullptr);
    k_pool<<<1764, 256, 0, stream>>>(Qp, af);
    k_stageA<<<dim3(NCH, 128), 256, 0, stream>>>(Kp, Vp, af, b1, part);
    k_reduceA<<<128, 256, 0, stream>>>(part, agv);
    k_stageB<<<dim3(13, 128), 256, 0, stream>>>(Qp, af, agv, b2, out);
    k_conv<<<28224, 256, 0, stream>>>(Vp, out, dwcw, gam, bet, xb /*pre*/);
    k_gemm<1><<<dim3(9, 392), 256, 0, stream>>>(xb /*pre*/, wpT, nullptr, nullptr, nullptr, out, projb);
}

// Round 4
// 832.913 us; speedup vs baseline: 1.7076x; 1.7076x over previous
//
#include <hip/hip_runtime.h>
#include <stdint.h>

// ---------- types ----------
typedef unsigned short u16;
typedef u16   u16x4 __attribute__((ext_vector_type(4)));
typedef u16   u16x8 __attribute__((ext_vector_type(8)));
typedef float f32x4 __attribute__((ext_vector_type(4)));
typedef __bf16 bf16x8 __attribute__((ext_vector_type(8)));

// ---------- constants ----------
#define BB    16
#define NN    3136
#define CC    576
#define HEADS 8
#define HD    72
#define AGN   49
#define NTOT  1728
#define NCH   7                      // stageA chunks (448 tokens, 7 tiles of 64)
#define SCALE 0.1178511301977579f   // 72^-0.5

__device__ __forceinline__ u16 f2bf(float f) {
    unsigned u = __float_as_uint(f);
    return (u16)((u + 0x7fffu + ((u >> 16) & 1u)) >> 16);
}
__device__ __forceinline__ float bf2f(u16 u) {
    return __uint_as_float(((unsigned)u) << 16);
}

// ---------- cast x -> bf16 ----------
__global__ __launch_bounds__(256) void k_cast_x(const float* __restrict__ x, u16* __restrict__ xb) {
    size_t i = (size_t)blockIdx.x * 256 + threadIdx.x;
    f32x4 v = *(const f32x4*)(x + i * 4);
    u16x4 o; o[0] = f2bf(v[0]); o[1] = f2bf(v[1]); o[2] = f2bf(v[2]); o[3] = f2bf(v[3]);
    *(u16x4*)(xb + i * 4) = o;
}

// ---------- pack transposed bf16 weights ----------
__global__ __launch_bounds__(256) void k_prep_w(const float* __restrict__ Wq, const float* __restrict__ Wkv,
                                                const float* __restrict__ Wp,
                                                u16* __restrict__ wbT, u16* __restrict__ wpT) {
    int idx = blockIdx.x * 256 + threadIdx.x;
    if (idx < NTOT * CC) {
        int nn = idx / CC, kk = idx % CC;
        float v = (nn < CC) ? Wq[kk * CC + nn] : Wkv[kk * (2 * CC) + (nn - CC)];
        wbT[idx] = f2bf(v);
    } else {
        int j = idx - NTOT * CC;
        int nn = j / CC, kk = j % CC;
        wpT[j] = f2bf(Wp[kk * CC + nn]);
    }
}

// ---------- jax.image.resize 'linear' 7x7 -> 56x56 ----------
__device__ __forceinline__ float bilerp7(const float* __restrict__ g, int oy, int ox) {
    float cy = (oy - 3.5f) * 0.125f;
    float cx = (ox - 3.5f) * 0.125f;
    float fy0 = floorf(cy), fx0 = floorf(cx);
    float ty = cy - fy0, tx = cx - fx0;
    int iy0 = (int)fy0, ix0 = (int)fx0;
    int y0 = min(6, max(0, iy0)), y1 = min(6, max(0, iy0 + 1));
    int x0 = min(6, max(0, ix0)), x1 = min(6, max(0, ix0 + 1));
    float g00 = g[y0 * 7 + x0], g01 = g[y0 * 7 + x1];
    float g10 = g[y1 * 7 + x0], g11 = g[y1 * 7 + x1];
    return (1.f - ty) * ((1.f - tx) * g00 + tx * g01) + ty * ((1.f - tx) * g10 + tx * g11);
}

// bias1 layout: [h][n][49]  (agent innermost, to init MFMA accumulators)
__global__ __launch_bounds__(256) void k_bias1(const float* __restrict__ an, const float* __restrict__ ah,
                                               const float* __restrict__ aw, float* __restrict__ b1) {
    int idx = blockIdx.x * 256 + threadIdx.x;            // 8*3136*49
    int ag = idx % AGN; int r = idx / AGN; int n = r % NN; int h = r / NN;
    int y = n / 56, x = n % 56;
    float v = bilerp7(an + (h * AGN + ag) * 49, y, x);
    b1[idx] = v + ah[(h * AGN + ag) * 56 + y] + aw[(h * AGN + ag) * 56 + x];
}

__global__ __launch_bounds__(256) void k_bias2(const float* __restrict__ na, const float* __restrict__ ha,
                                               const float* __restrict__ wa, float* __restrict__ b2) {
    int idx = blockIdx.x * 256 + threadIdx.x;
    int ag = idx % AGN; int r = idx / AGN; int n = r % NN; int h = r / NN;
    int y = n / 56, x = n % 56;
    float v = bilerp7(na + (h * AGN + ag) * 49, y, x);
    b2[idx] = v + ha[(h * 56 + y) * AGN + ag] + wa[(h * 56 + x) * AGN + ag];
}

// ---------- MFMA GEMM: A[M x 576] @ Bt[N x 576]^T,  BM=128 BN=64 BK=64 ----------
template<int MODE>
__global__ __launch_bounds__(256) void k_gemm(const u16* __restrict__ A, const u16* __restrict__ Bt,
                                              u16* __restrict__ Qp, u16* __restrict__ Kp, u16* __restrict__ Vp,
                                              float* __restrict__ Cf, const float* __restrict__ bias) {
    __shared__ u16 Asm[128 * 64];
    __shared__ u16 Bsm[64 * 64];
    const int t = threadIdx.x, lane = t & 63, wid = t >> 6;
    const int wm = wid & 1, wn = wid >> 1;
    const int row0 = blockIdx.y * 128, col0 = blockIdx.x * 64;
    const int lr = lane & 15, lk = lane >> 4;
    f32x4 acc[4][2];
#pragma unroll
    for (int m = 0; m < 4; m++)
#pragma unroll
        for (int n2 = 0; n2 < 2; n2++) acc[m][n2] = (f32x4)0.f;

    for (int kt = 0; kt < 9; ++kt) {
        const int k0 = kt * 64;
#pragma unroll
        for (int it = 0; it < 4; ++it) {
            int flat = it * 256 + wid * 64 + lane;
            int r = flat >> 3, lc = (flat & 7) ^ (r & 7);
            const u16* src = A + (size_t)(row0 + r) * CC + k0 + lc * 8;
            __builtin_amdgcn_global_load_lds((const __attribute__((address_space(1))) void*)src,
                                             (__attribute__((address_space(3))) void*)(&Asm[(it * 256 + wid * 64) * 8]),
                                             16, 0, 0);
        }
#pragma unroll
        for (int it = 0; it < 2; ++it) {
            int flat = it * 256 + wid * 64 + lane;
            int r = flat >> 3, lc = (flat & 7) ^ (r & 7);
            const u16* src = Bt + (size_t)(col0 + r) * CC + k0 + lc * 8;
            __builtin_amdgcn_global_load_lds((const __attribute__((address_space(1))) void*)src,
                                             (__attribute__((address_space(3))) void*)(&Bsm[(it * 256 + wid * 64) * 8]),
                                             16, 0, 0);
        }
        __syncthreads();
#pragma unroll
        for (int kk = 0; kk < 2; ++kk) {
            const int klocal2 = (kk * 32 + lk * 8) * 2;
            bf16x8 av[4], bv[2];
#pragma unroll
            for (int m = 0; m < 4; m++) {
                int row = wm * 64 + m * 16 + lr;
                av[m] = *(const bf16x8*)((const char*)Asm + row * 128 + (klocal2 ^ ((row & 7) << 4)));
            }
#pragma unroll
            for (int n2 = 0; n2 < 2; n2++) {
                int row = wn * 32 + n2 * 16 + lr;
                bv[n2] = *(const bf16x8*)((const char*)Bsm + row * 128 + (klocal2 ^ ((row & 7) << 4)));
            }
#pragma unroll
            for (int m = 0; m < 4; m++)
#pragma unroll
                for (int n2 = 0; n2 < 2; n2++)
                    acc[m][n2] = __builtin_amdgcn_mfma_f32_16x16x32_bf16(av[m], bv[n2], acc[m][n2], 0, 0, 0);
        }
        __syncthreads();
    }
#pragma unroll
    for (int n2 = 0; n2 < 2; n2++) {
        int cgl = col0 + wn * 32 + n2 * 16 + lr;
        if (MODE == 0) {
            int which = cgl / 576;
            int rem = cgl - which * 576;
            int hh = rem / 72;
            int dd = rem - hh * 72;
            u16* dst = which == 0 ? Qp : (which == 1 ? Kp : Vp);
#pragma unroll
            for (int m = 0; m < 4; m++)
#pragma unroll
                for (int j = 0; j < 4; j++) {
                    int rgl = row0 + wm * 64 + m * 16 + lk * 4 + j;
                    int b = rgl / NN, n = rgl - b * NN;
                    dst[((size_t)(b * 8 + hh) * NN + n) * 72 + dd] = f2bf(acc[m][n2][j]);
                }
        } else {
#pragma unroll
            for (int m = 0; m < 4; m++)
#pragma unroll
                for (int j = 0; j < 4; j++) {
                    int rgl = row0 + wm * 64 + m * 16 + lk * 4 + j;
                    Cf[(size_t)rgl * 576 + cgl] = acc[m][n2][j] + bias[cgl];
                }
        }
    }
}

// ---------- agent pooling (head-planar q): a[b][ag][c] ----------
__global__ __launch_bounds__(256) void k_pool(const u16* __restrict__ Qp, float* __restrict__ a_f) {
    int idx = blockIdx.x * 256 + threadIdx.x;
    int c = idx % CC; int r = idx / CC; int ag = r % AGN; int b = r / AGN;
    int hh = c / 72, dd = c - hh * 72;
    int p1 = ag / 7, p2 = ag % 7;
    const u16* base = Qp + ((size_t)(b * 8 + hh) * NN) * 72 + dd;
    float s = 0.f;
    for (int i = 0; i < 8; i++)
        for (int j = 0; j < 8; j++)
            s += bf2f(base[(size_t)((p1 * 8 + i) * 56 + p2 * 8 + j) * 72]);
    a_f[idx] = s * 0.015625f;
}

// ---------- stage A (MFMA): S^T = mfma(K, a), online softmax per agent-col, PV = mfma(P, V^T) ----------
__global__ __launch_bounds__(256) void k_stageA(const u16* __restrict__ Kp, const u16* __restrict__ Vp,
                                                const float* __restrict__ a_f, const float* __restrict__ b1,
                                                float* __restrict__ part) {
    const int t = threadIdx.x, lane = t & 63, w = t >> 6;
    const int c = lane & 15, g = lane >> 4;
    const int bh = blockIdx.y, b = bh >> 3, h = bh & 7;
    const int chunk = blockIdx.x;                        // 0..6

    __shared__ u16 A_lds[64][104];                       // agents (bf16, scaled), K-pad 72..95 = 0
    __shared__ u16 K_lds[64][104];                       // K tile, K-pad zeroed once
    __shared__ u16 Vt[80][72];                           // V^T: [d][n], rows 72..79 = 0
    __shared__ u16 P_lds[64][72];                        // P (bf16): [agent][n]

    // zero pads (once; data regions overwritten per tile never touch pads)
    for (int i = t; i < 64 * 104; i += 256) {
        int r = i / 104, cc = i - r * 104;
        if (cc >= 72 || r >= 49) A_lds[r][cc] = 0;
        if (cc >= 72) K_lds[r][cc] = 0;
    }
    for (int i = t; i < 8 * 72; i += 256) Vt[72 + i / 72][i % 72] = 0;
    // load agents (scaled) as bf16
    for (int i = t; i < 49 * 72; i += 256) {
        int r = i / 72, d = i - r * 72;
        A_lds[r][d] = f2bf(a_f[(size_t)(b * 49 + r) * CC + h * 72 + d] * SCALE);
    }
    __syncthreads();

    // hoisted agent b-frags (A_lds is read-only from here)
    bf16x8 bfA[3];
#pragma unroll
    for (int ks = 0; ks < 3; ++ks) bfA[ks] = *(const bf16x8*)&A_lds[16 * w + c][8 * g + 32 * ks];

    float m_run = -1e30f, l_run = 0.f;                   // state for agent 16w+c (replicated over g)
    f32x4 acc[5];
#pragma unroll
    for (int dt = 0; dt < 5; ++dt) acc[dt] = (f32x4)0.f;

    const u16* kb = Kp + ((size_t)(b * 8 + h) * NN + chunk * 448) * 72;
    const u16* vb = Vp + ((size_t)(b * 8 + h) * NN + chunk * 448) * 72;
    const int arow = min(16 * w + c, 48);

    for (int tile = 0; tile < 7; ++tile) {
        // ---- stage K (coalesced, b128 LDS writes) ----
        for (int i = t; i < 576; i += 256) {
            int nl = i / 9, ch = i - nl * 9;
            u16x8 kd = *(const u16x8*)(kb + (size_t)tile * 4608 + i * 8);
            *(u16x8*)&K_lds[nl][ch * 8] = kd;
        }
        // ---- stage V transposed (2-way-conflict-free scalar writes) ----
        for (int i = t; i < 576; i += 256) {
            int ch = i >> 6, nl = i & 63;
            u16x8 vd = *(const u16x8*)(vb + (size_t)tile * 4608 + (nl * 9 + ch) * 8);
#pragma unroll
            for (int j = 0; j < 8; j++) Vt[ch * 8 + j][nl] = vd[j];
        }
        __syncthreads();

        // ---- S^T: rows = n (local 0..63), cols = agents; wave w owns agent cols [16w,16w+16) ----
        f32x4 sT[4];
        const int nbase = chunk * 448 + tile * 64 + 4 * g;
#pragma unroll
        for (int nm = 0; nm < 4; ++nm) {
            f32x4 sv;
#pragma unroll
            for (int j = 0; j < 4; j++)
                sv[j] = b1[(size_t)(h * NN + nbase + 16 * nm + j) * AGN + arow];
#pragma unroll
            for (int ks = 0; ks < 3; ++ks) {
                bf16x8 af = *(const bf16x8*)&K_lds[16 * nm + c][8 * g + 32 * ks];
                sv = __builtin_amdgcn_mfma_f32_16x16x32_bf16(af, bfA[ks], sv, 0, 0, 0);
            }
            sT[nm] = sv;
        }

        // ---- online softmax for agent col 16w+c: 16 in-lane values + 2 shuffle hops ----
        float mt = sT[0][0];
#pragma unroll
        for (int nm = 0; nm < 4; ++nm)
#pragma unroll
            for (int j = 0; j < 4; j++) mt = fmaxf(mt, sT[nm][j]);
        mt = fmaxf(mt, __shfl_xor(mt, 16, 64));
        mt = fmaxf(mt, __shfl_xor(mt, 32, 64));
        float mnew = fmaxf(m_run, mt);
        float ps = 0.f;
#pragma unroll
        for (int nm = 0; nm < 4; ++nm) {
            float p0 = __expf(sT[nm][0] - mnew);
            float p1 = __expf(sT[nm][1] - mnew);
            float p2 = __expf(sT[nm][2] - mnew);
            float p3 = __expf(sT[nm][3] - mnew);
            ps += (p0 + p1) + (p2 + p3);
            unsigned pk01 = ((unsigned)f2bf(p1) << 16) | f2bf(p0);
            unsigned pk23 = ((unsigned)f2bf(p3) << 16) | f2bf(p2);
            unsigned* dst = (unsigned*)&P_lds[16 * w + c][16 * nm + 4 * g];
            dst[0] = pk01; dst[1] = pk23;
        }
        ps += __shfl_xor(ps, 16, 64);
        ps += __shfl_xor(ps, 32, 64);
        float rsc = __expf(m_run - mnew);
        l_run = l_run * rsc + ps;
        m_run = mnew;

        // ---- PV: AV[agent][d] += P @ V ; rescale acc by r per agent-row ----
        float rj[4];
#pragma unroll
        for (int j = 0; j < 4; j++) rj[j] = __shfl(rsc, 4 * g + j, 64);
        bf16x8 pa[2];
#pragma unroll
        for (int ks = 0; ks < 2; ++ks) pa[ks] = *(const bf16x8*)&P_lds[16 * w + c][8 * g + 32 * ks];
#pragma unroll
        for (int dt = 0; dt < 5; ++dt) {
            f32x4 a0 = acc[dt];
#pragma unroll
            for (int j = 0; j < 4; j++) a0[j] *= rj[j];
#pragma unroll
            for (int ks = 0; ks < 2; ++ks) {
                bf16x8 vf = *(const bf16x8*)&Vt[16 * dt + c][8 * g + 32 * ks];
                a0 = __builtin_amdgcn_mfma_f32_16x16x32_bf16(pa[ks], vf, a0, 0, 0, 0);
            }
            acc[dt] = a0;
        }
        __syncthreads();                                 // before next tile's staging overwrites K/Vt
    }

    // ---- write partials ----
    const size_t pbase = (size_t)(bh * NCH + chunk) * (49 * 74);
#pragma unroll
    for (int dt = 0; dt < 5; ++dt) {
        int d = 16 * dt + c;
        if (d < 72) {
#pragma unroll
            for (int j = 0; j < 4; j++) {
                int agent = 16 * w + 4 * g + j;
                if (agent < 49) part[pbase + agent * 74 + d] = acc[dt][j];
            }
        }
    }
    if (g == 0) {
        int agent = 16 * w + c;
        if (agent < 49) {
            part[pbase + agent * 74 + 72] = m_run;
            part[pbase + agent * 74 + 73] = l_run;
        }
    }
}

// ---------- reduce partials across NCH chunks ----------
__global__ __launch_bounds__(256) void k_reduceA(const float* __restrict__ part, float* __restrict__ agv) {
    const int bh = blockIdx.x, t = threadIdx.x;
    const float* pb = part + (size_t)bh * NCH * (49 * 74);
    for (int idx = t; idx < 49 * 72; idx += 256) {
        int row = idx / 72, d = idx - row * 72;
        float m = -1e30f;
#pragma unroll
        for (int c = 0; c < NCH; c++) m = fmaxf(m, pb[c * (49 * 74) + row * 74 + 72]);
        float accv = 0.f, l = 0.f;
#pragma unroll
        for (int c = 0; c < NCH; c++) {
            const float* pc = pb + c * (49 * 74) + row * 74;
            float e = __expf(pc[72] - m);
            accv += pc[d] * e;
            l += pc[73] * e;
        }
        agv[(size_t)(bh * 49 + row) * 72 + d] = accv / l;
    }
}

// ---------- stage B: per-token softmax over 49 agents + PV ----------
__global__ __launch_bounds__(256) void k_stageB(const u16* __restrict__ Qp, const float* __restrict__ a_f,
                                                const float* __restrict__ agent_v, const float* __restrict__ bias2,
                                                float* __restrict__ outatt) {
    const int t = threadIdx.x;
    const int bh = blockIdx.y; const int b = bh >> 3, h = bh & 7;
    __shared__ float a_s[49][72];
    __shared__ float av[49][72];
    for (int idx = t; idx < 49 * 72; idx += 256) {
        int ag = idx / 72, dd = idx % 72;
        a_s[ag][dd] = a_f[(size_t)(b * AGN + ag) * CC + h * HD + dd] * SCALE;
        av[ag][dd]  = agent_v[(size_t)(bh * AGN + ag) * HD + dd];
    }
    __syncthreads();
    const int n = blockIdx.x * 256 + t;
    if (n >= NN) return;
    const u16* qp = Qp + ((size_t)(b * 8 + h) * NN + n) * 72;
    const float* brow = bias2 + ((size_t)h * NN + n) * AGN;
    float s[49];
#pragma unroll
    for (int ag = 0; ag < 49; ++ag) s[ag] = brow[ag];
    for (int ch = 0; ch < 9; ++ch) {
        u16x8 qc = *(const u16x8*)(qp + ch * 8);
        float qf[8];
#pragma unroll
        for (int j = 0; j < 8; j++) qf[j] = bf2f(qc[j]);
#pragma unroll
        for (int ag = 0; ag < 49; ++ag) {
            float a2 = s[ag];
#pragma unroll
            for (int j = 0; j < 8; j++) a2 += qf[j] * a_s[ag][ch * 8 + j];
            s[ag] = a2;
        }
    }
    float mx = -1e30f;
#pragma unroll
    for (int ag = 0; ag < 49; ++ag) mx = fmaxf(mx, s[ag]);
    float l = 0.f;
#pragma unroll
    for (int ag = 0; ag < 49; ++ag) { float p = __expf(s[ag] - mx); s[ag] = p; l += p; }
    float inv = 1.f / l;
#pragma unroll
    for (int ag = 0; ag < 49; ++ag) s[ag] *= inv;
    float* op = outatt + (size_t)(b * NN + n) * CC + h * HD;
    for (int dc = 0; dc < 9; ++dc) {
        float o8[8] = {0.f, 0.f, 0.f, 0.f, 0.f, 0.f, 0.f, 0.f};
#pragma unroll
        for (int ag = 0; ag < 49; ++ag)
#pragma unroll
            for (int j = 0; j < 8; j++) o8[j] += s[ag] * av[ag][dc * 8 + j];
#pragma unroll
        for (int j = 0; j < 8; j++) op[dc * 8 + j] = o8[j];
    }
}

// ---------- depthwise 3x3 conv + affine + relu + add, emit bf16 'pre' ----------
__global__ __launch_bounds__(256) void k_conv(const u16* __restrict__ Vp, const float* __restrict__ outatt,
                                              const float* __restrict__ w, const float* __restrict__ gamma,
                                              const float* __restrict__ beta, u16* __restrict__ pre) {
    int idx = blockIdx.x * 256 + threadIdx.x;
    int c4 = idx % 144; int rest = idx / 144; int n = rest % NN; int b = rest / NN;
    int y = n / 56, x = n % 56;
    int c0 = c4 * 4;
    int hh = c0 / 72, dl = c0 - hh * 72;
    const u16* vbase = Vp + ((size_t)(b * 8 + hh) * NN) * 72 + dl;
    float a0 = 0.f, a1 = 0.f, a2 = 0.f, a3 = 0.f;
#pragma unroll
    for (int dy = -1; dy <= 1; ++dy) {
        int yy = y + dy; if (yy < 0 || yy > 55) continue;
#pragma unroll
        for (int dx = -1; dx <= 1; ++dx) {
            int xx = x + dx; if (xx < 0 || xx > 55) continue;
            u16x4 vv = *(const u16x4*)(vbase + (size_t)(yy * 56 + xx) * 72);
            int tap = (dy + 1) * 3 + (dx + 1);
            a0 += bf2f(vv[0]) * w[(c0 + 0) * 9 + tap];
            a1 += bf2f(vv[1]) * w[(c0 + 1) * 9 + tap];
            a2 += bf2f(vv[2]) * w[(c0 + 2) * 9 + tap];
            a3 += bf2f(vv[3]) * w[(c0 + 3) * 9 + tap];
        }
    }
    const float* oa = outatt + (size_t)(b * NN + n) * CC + c0;
    f32x4 o = *(const f32x4*)oa;
    float y0 = fmaxf(a0 * gamma[c0 + 0] + beta[c0 + 0], 0.f);
    float y1 = fmaxf(a1 * gamma[c0 + 1] + beta[c0 + 1], 0.f);
    float y2 = fmaxf(a2 * gamma[c0 + 2] + beta[c0 + 2], 0.f);
    float y3 = fmaxf(a3 * gamma[c0 + 3] + beta[c0 + 3], 0.f);
    u16x4 rr; rr[0] = f2bf(o[0] + y0); rr[1] = f2bf(o[1] + y1); rr[2] = f2bf(o[2] + y2); rr[3] = f2bf(o[3] + y3);
    *(u16x4*)(pre + (size_t)(b * NN + n) * CC + c0) = rr;
}

// ---------- launch ----------
extern "C" void kernel_launch(void* const* d_in, const int* in_sizes, int n_in,
                              void* d_out, int out_size, void* d_ws, size_t ws_size,
                              hipStream_t stream) {
    const float* x     = (const float*)d_in[0];
    const float* Wq    = (const float*)d_in[1];
    const float* Wkv   = (const float*)d_in[2];
    const float* an_b  = (const float*)d_in[3];
    const float* na_b  = (const float*)d_in[4];
    const float* ah_b  = (const float*)d_in[5];
    const float* aw_b  = (const float*)d_in[6];
    const float* ha_b  = (const float*)d_in[7];
    const float* wa_b  = (const float*)d_in[8];
    const float* dwcw  = (const float*)d_in[9];
    const float* gam   = (const float*)d_in[10];
    const float* bet   = (const float*)d_in[11];
    const float* projw = (const float*)d_in[12];
    const float* projb = (const float*)d_in[13];
    float* out = (float*)d_out;

    char* ws = (char*)d_ws;
    u16* wbT  = (u16*)(ws + 0);                          //  1,990,656
    u16* wpT  = (u16*)(ws + 1990656);                    //    663,552
    u16* xb   = (u16*)(ws + 2654208);                    // 57,802,752 (reused: stageA partials, then 'pre')
    u16* Qp   = (u16*)(ws + 60456960);                   // 57,802,752
    u16* Kp   = (u16*)(ws + 118259712);                  // 57,802,752
    u16* Vp   = (u16*)(ws + 176062464);                  // 57,802,752
    float* af = (float*)(ws + 233865216);                //  1,806,336
    float* agv= (float*)(ws + 235671552);                //  1,806,336
    float* b1 = (float*)(ws + 237477888);                //  4,917,248  [h][n][49]
    float* b2 = (float*)(ws + 242395136);                //  4,917,248
    float* part = (float*)xb;                            // 12,995,584 (inside xb region)

    k_cast_x<<<28224, 256, 0, stream>>>(x, xb);
    k_prep_w<<<5184, 256, 0, stream>>>(Wq, Wkv, projw, wbT, wpT);
    k_bias1<<<4802, 256, 0, stream>>>(an_b, ah_b, aw_b, b1);
    k_bias2<<<4802, 256, 0, stream>>>(na_b, ha_b, wa_b, b2);
    k_gemm<0><<<dim3(27, 392), 256, 0, stream>>>(xb, wbT, Qp, Kp, Vp, nullptr, nullptr);
    k_pool<<<1764, 256, 0, stream>>>(Qp, af);
    k_stageA<<<dim3(NCH, 128), 256, 0, stream>>>(Kp, Vp, af, b1, part);
    k_reduceA<<<128, 256, 0, stream>>>(part, agv);
    k_stageB<<<dim3(13, 128), 256, 0, stream>>>(Qp, af, agv, b2, out);
    k_conv<<<28224, 256, 0, stream>>>(Vp, out, dwcw, gam, bet, xb /*pre*/);
    k_gemm<1><<<dim3(9, 392), 256, 0, stream>>>(xb /*pre*/, wpT, nullptr, nullptr, nullptr, out, projb);
}

// Round 5
// 627.516 us; speedup vs baseline: 2.2665x; 1.3273x over previous
//
#include <hip/hip_runtime.h>
#include <stdint.h>

// ---------- types ----------
typedef unsigned short u16;
typedef u16   u16x4 __attribute__((ext_vector_type(4)));
typedef u16   u16x8 __attribute__((ext_vector_type(8)));
typedef float f32x4 __attribute__((ext_vector_type(4)));
typedef __bf16 bf16x8 __attribute__((ext_vector_type(8)));

// ---------- constants ----------
#define BB    16
#define NN    3136
#define CC    576
#define HEADS 8
#define HD    72
#define AGN   49
#define NTOT  1728
#define NCH   7                      // stageA chunks (448 tokens, 7 tiles of 64)
#define SCALE 0.1178511301977579f   // 72^-0.5

__device__ __forceinline__ u16 f2bf(float f) {
    unsigned u = __float_as_uint(f);
    return (u16)((u + 0x7fffu + ((u >> 16) & 1u)) >> 16);
}
__device__ __forceinline__ float bf2f(u16 u) {
    return __uint_as_float(((unsigned)u) << 16);
}

// ---------- cast x -> bf16 ----------
__global__ __launch_bounds__(256) void k_cast_x(const float* __restrict__ x, u16* __restrict__ xb) {
    size_t i = (size_t)blockIdx.x * 256 + threadIdx.x;
    f32x4 v = *(const f32x4*)(x + i * 4);
    u16x4 o; o[0] = f2bf(v[0]); o[1] = f2bf(v[1]); o[2] = f2bf(v[2]); o[3] = f2bf(v[3]);
    *(u16x4*)(xb + i * 4) = o;
}

// ---------- pack transposed bf16 weights ----------
__global__ __launch_bounds__(256) void k_prep_w(const float* __restrict__ Wq, const float* __restrict__ Wkv,
                                                const float* __restrict__ Wp,
                                                u16* __restrict__ wbT, u16* __restrict__ wpT) {
    int idx = blockIdx.x * 256 + threadIdx.x;
    if (idx < NTOT * CC) {
        int nn = idx / CC, kk = idx % CC;
        float v = (nn < CC) ? Wq[kk * CC + nn] : Wkv[kk * (2 * CC) + (nn - CC)];
        wbT[idx] = f2bf(v);
    } else {
        int j = idx - NTOT * CC;
        int nn = j / CC, kk = j % CC;
        wpT[j] = f2bf(Wp[kk * CC + nn]);
    }
}

// ---------- jax.image.resize 'linear' 7x7 -> 56x56 ----------
__device__ __forceinline__ float bilerp7(const float* __restrict__ g, int oy, int ox) {
    float cy = (oy - 3.5f) * 0.125f;
    float cx = (ox - 3.5f) * 0.125f;
    float fy0 = floorf(cy), fx0 = floorf(cx);
    float ty = cy - fy0, tx = cx - fx0;
    int iy0 = (int)fy0, ix0 = (int)fx0;
    int y0 = min(6, max(0, iy0)), y1 = min(6, max(0, iy0 + 1));
    int x0 = min(6, max(0, ix0)), x1 = min(6, max(0, ix0 + 1));
    float g00 = g[y0 * 7 + x0], g01 = g[y0 * 7 + x1];
    float g10 = g[y1 * 7 + x0], g11 = g[y1 * 7 + x1];
    return (1.f - ty) * ((1.f - tx) * g00 + tx * g01) + ty * ((1.f - tx) * g10 + tx * g11);
}

// bias1 layout: [h][n][49]  (agent innermost, to init MFMA accumulators)
__global__ __launch_bounds__(256) void k_bias1(const float* __restrict__ an, const float* __restrict__ ah,
                                               const float* __restrict__ aw, float* __restrict__ b1) {
    int idx = blockIdx.x * 256 + threadIdx.x;
    int ag = idx % AGN; int r = idx / AGN; int n = r % NN; int h = r / NN;
    int y = n / 56, x = n % 56;
    float v = bilerp7(an + (h * AGN + ag) * 49, y, x);
    b1[idx] = v + ah[(h * AGN + ag) * 56 + y] + aw[(h * AGN + ag) * 56 + x];
}

__global__ __launch_bounds__(256) void k_bias2(const float* __restrict__ na, const float* __restrict__ ha,
                                               const float* __restrict__ wa, float* __restrict__ b2) {
    int idx = blockIdx.x * 256 + threadIdx.x;
    int ag = idx % AGN; int r = idx / AGN; int n = r % NN; int h = r / NN;
    int y = n / 56, x = n % 56;
    float v = bilerp7(na + (h * AGN + ag) * 49, y, x);
    b2[idx] = v + ha[(h * 56 + y) * AGN + ag] + wa[(h * 56 + x) * AGN + ag];
}

// ---------- MFMA GEMM: A[M x 576] @ Bt[NB x 576]^T,  BM=128 BN=128 BK=64, 4 waves ----------
// MODE 0: scatter bf16 to head-planar Qp/Kp/Vp (NB=1728); MODE 1: f32 + bias to Cf (NB=576)
template<int MODE>
__global__ __launch_bounds__(256) void k_gemm(const u16* __restrict__ A, const u16* __restrict__ Bt,
                                              u16* __restrict__ Qp, u16* __restrict__ Kp, u16* __restrict__ Vp,
                                              float* __restrict__ Cf, const float* __restrict__ bias) {
    const int NB = (MODE == 0) ? NTOT : CC;
    __shared__ u16 Asm[128 * 64];
    __shared__ u16 Bsm[128 * 64];
    const int t = threadIdx.x, lane = t & 63, wid = t >> 6;
    const int wm = wid & 1, wn = wid >> 1;
    const int row0 = blockIdx.y * 128, col0 = blockIdx.x * 128;
    const int lr = lane & 15, lk = lane >> 4;
    f32x4 acc[4][4];
#pragma unroll
    for (int m = 0; m < 4; m++)
#pragma unroll
        for (int n2 = 0; n2 < 4; n2++) acc[m][n2] = (f32x4)0.f;

    for (int kt = 0; kt < 9; ++kt) {
        const int k0 = kt * 64;
#pragma unroll
        for (int it = 0; it < 4; ++it) {
            int flat = it * 256 + wid * 64 + lane;
            int r = flat >> 3, lc = (flat & 7) ^ (r & 7);
            const u16* src = A + (size_t)(row0 + r) * CC + k0 + lc * 8;
            __builtin_amdgcn_global_load_lds((const __attribute__((address_space(1))) void*)src,
                                             (__attribute__((address_space(3))) void*)(&Asm[(it * 256 + wid * 64) * 8]),
                                             16, 0, 0);
        }
#pragma unroll
        for (int it = 0; it < 4; ++it) {
            int flat = it * 256 + wid * 64 + lane;
            int r = flat >> 3, lc = (flat & 7) ^ (r & 7);
            int brow = min(col0 + r, NB - 1);             // clamp N-tail
            const u16* src = Bt + (size_t)brow * CC + k0 + lc * 8;
            __builtin_amdgcn_global_load_lds((const __attribute__((address_space(1))) void*)src,
                                             (__attribute__((address_space(3))) void*)(&Bsm[(it * 256 + wid * 64) * 8]),
                                             16, 0, 0);
        }
        __syncthreads();
#pragma unroll
        for (int kk = 0; kk < 2; ++kk) {
            const int klocal2 = (kk * 32 + lk * 8) * 2;
            bf16x8 av[4], bv[4];
#pragma unroll
            for (int m = 0; m < 4; m++) {
                int row = wm * 64 + m * 16 + lr;
                av[m] = *(const bf16x8*)((const char*)Asm + row * 128 + (klocal2 ^ ((row & 7) << 4)));
            }
#pragma unroll
            for (int n2 = 0; n2 < 4; n2++) {
                int row = wn * 64 + n2 * 16 + lr;
                bv[n2] = *(const bf16x8*)((const char*)Bsm + row * 128 + (klocal2 ^ ((row & 7) << 4)));
            }
#pragma unroll
            for (int m = 0; m < 4; m++)
#pragma unroll
                for (int n2 = 0; n2 < 4; n2++)
                    acc[m][n2] = __builtin_amdgcn_mfma_f32_16x16x32_bf16(av[m], bv[n2], acc[m][n2], 0, 0, 0);
        }
        __syncthreads();
    }
#pragma unroll
    for (int n2 = 0; n2 < 4; n2++) {
        int cgl = col0 + wn * 64 + n2 * 16 + lr;
        if (cgl >= NB) continue;
        if (MODE == 0) {
            int which = cgl / 576;
            int rem = cgl - which * 576;
            int hh = rem / 72;
            int dd = rem - hh * 72;
            u16* dst = which == 0 ? Qp : (which == 1 ? Kp : Vp);
#pragma unroll
            for (int m = 0; m < 4; m++)
#pragma unroll
                for (int j = 0; j < 4; j++) {
                    int rgl = row0 + wm * 64 + m * 16 + lk * 4 + j;
                    int b = rgl / NN, n = rgl - b * NN;
                    dst[((size_t)(b * 8 + hh) * NN + n) * 72 + dd] = f2bf(acc[m][n2][j]);
                }
        } else {
#pragma unroll
            for (int m = 0; m < 4; m++)
#pragma unroll
                for (int j = 0; j < 4; j++) {
                    int rgl = row0 + wm * 64 + m * 16 + lk * 4 + j;
                    Cf[(size_t)rgl * 576 + cgl] = acc[m][n2][j] + bias[cgl];
                }
        }
    }
}

// ---------- agent pooling (head-planar q): a[b][ag][c] ----------
__global__ __launch_bounds__(256) void k_pool(const u16* __restrict__ Qp, float* __restrict__ a_f) {
    int idx = blockIdx.x * 256 + threadIdx.x;
    int c = idx % CC; int r = idx / CC; int ag = r % AGN; int b = r / AGN;
    int hh = c / 72, dd = c - hh * 72;
    int p1 = ag / 7, p2 = ag % 7;
    const u16* base = Qp + ((size_t)(b * 8 + hh) * NN) * 72 + dd;
    float s = 0.f;
    for (int i = 0; i < 8; i++)
        for (int j = 0; j < 8; j++)
            s += bf2f(base[(size_t)((p1 * 8 + i) * 56 + p2 * 8 + j) * 72]);
    a_f[idx] = s * 0.015625f;
}

// ---------- stage A (MFMA): S^T = mfma(K, a), online softmax per agent-col, PV = mfma(P, V^T) ----------
__global__ __launch_bounds__(256) void k_stageA(const u16* __restrict__ Kp, const u16* __restrict__ Vp,
                                                const float* __restrict__ a_f, const float* __restrict__ b1,
                                                float* __restrict__ part) {
    const int t = threadIdx.x, lane = t & 63, w = t >> 6;
    const int c = lane & 15, g = lane >> 4;
    const int bh = blockIdx.y, b = bh >> 3, h = bh & 7;
    const int chunk = blockIdx.x;                        // 0..6

    __shared__ u16 A_lds[64][104];
    __shared__ u16 K_lds[64][104];
    __shared__ u16 Vt[80][72];
    __shared__ u16 P_lds[64][72];

    for (int i = t; i < 64 * 104; i += 256) {
        int r = i / 104, cc = i - r * 104;
        if (cc >= 72 || r >= 49) A_lds[r][cc] = 0;
        if (cc >= 72) K_lds[r][cc] = 0;
    }
    for (int i = t; i < 8 * 72; i += 256) Vt[72 + i / 72][i % 72] = 0;
    for (int i = t; i < 49 * 72; i += 256) {
        int r = i / 72, d = i - r * 72;
        A_lds[r][d] = f2bf(a_f[(size_t)(b * 49 + r) * CC + h * 72 + d] * SCALE);
    }
    __syncthreads();

    bf16x8 bfA[3];
#pragma unroll
    for (int ks = 0; ks < 3; ++ks) bfA[ks] = *(const bf16x8*)&A_lds[16 * w + c][8 * g + 32 * ks];

    float m_run = -1e30f, l_run = 0.f;
    f32x4 acc[5];
#pragma unroll
    for (int dt = 0; dt < 5; ++dt) acc[dt] = (f32x4)0.f;

    const u16* kb = Kp + ((size_t)(b * 8 + h) * NN + chunk * 448) * 72;
    const u16* vb = Vp + ((size_t)(b * 8 + h) * NN + chunk * 448) * 72;
    const int arow = min(16 * w + c, 48);

    for (int tile = 0; tile < 7; ++tile) {
        for (int i = t; i < 576; i += 256) {
            int nl = i / 9, ch = i - nl * 9;
            u16x8 kd = *(const u16x8*)(kb + (size_t)tile * 4608 + i * 8);
            *(u16x8*)&K_lds[nl][ch * 8] = kd;
        }
        for (int i = t; i < 576; i += 256) {
            int ch = i >> 6, nl = i & 63;
            u16x8 vd = *(const u16x8*)(vb + (size_t)tile * 4608 + (nl * 9 + ch) * 8);
#pragma unroll
            for (int j = 0; j < 8; j++) Vt[ch * 8 + j][nl] = vd[j];
        }
        __syncthreads();

        f32x4 sT[4];
        const int nbase = chunk * 448 + tile * 64 + 4 * g;
#pragma unroll
        for (int nm = 0; nm < 4; ++nm) {
            f32x4 sv;
#pragma unroll
            for (int j = 0; j < 4; j++)
                sv[j] = b1[(size_t)(h * NN + nbase + 16 * nm + j) * AGN + arow];
#pragma unroll
            for (int ks = 0; ks < 3; ++ks) {
                bf16x8 af = *(const bf16x8*)&K_lds[16 * nm + c][8 * g + 32 * ks];
                sv = __builtin_amdgcn_mfma_f32_16x16x32_bf16(af, bfA[ks], sv, 0, 0, 0);
            }
            sT[nm] = sv;
        }

        float mt = sT[0][0];
#pragma unroll
        for (int nm = 0; nm < 4; ++nm)
#pragma unroll
            for (int j = 0; j < 4; j++) mt = fmaxf(mt, sT[nm][j]);
        mt = fmaxf(mt, __shfl_xor(mt, 16, 64));
        mt = fmaxf(mt, __shfl_xor(mt, 32, 64));
        float mnew = fmaxf(m_run, mt);
        float ps = 0.f;
#pragma unroll
        for (int nm = 0; nm < 4; ++nm) {
            float p0 = __expf(sT[nm][0] - mnew);
            float p1 = __expf(sT[nm][1] - mnew);
            float p2 = __expf(sT[nm][2] - mnew);
            float p3 = __expf(sT[nm][3] - mnew);
            ps += (p0 + p1) + (p2 + p3);
            unsigned pk01 = ((unsigned)f2bf(p1) << 16) | f2bf(p0);
            unsigned pk23 = ((unsigned)f2bf(p3) << 16) | f2bf(p2);
            unsigned* dst = (unsigned*)&P_lds[16 * w + c][16 * nm + 4 * g];
            dst[0] = pk01; dst[1] = pk23;
        }
        ps += __shfl_xor(ps, 16, 64);
        ps += __shfl_xor(ps, 32, 64);
        float rsc = __expf(m_run - mnew);
        l_run = l_run * rsc + ps;
        m_run = mnew;

        float rj[4];
#pragma unroll
        for (int j = 0; j < 4; j++) rj[j] = __shfl(rsc, 4 * g + j, 64);
        bf16x8 pa[2];
#pragma unroll
        for (int ks = 0; ks < 2; ++ks) pa[ks] = *(const bf16x8*)&P_lds[16 * w + c][8 * g + 32 * ks];
#pragma unroll
        for (int dt = 0; dt < 5; ++dt) {
            f32x4 a0 = acc[dt];
#pragma unroll
            for (int j = 0; j < 4; j++) a0[j] *= rj[j];
#pragma unroll
            for (int ks = 0; ks < 2; ++ks) {
                bf16x8 vf = *(const bf16x8*)&Vt[16 * dt + c][8 * g + 32 * ks];
                a0 = __builtin_amdgcn_mfma_f32_16x16x32_bf16(pa[ks], vf, a0, 0, 0, 0);
            }
            acc[dt] = a0;
        }
        __syncthreads();
    }

    const size_t pbase = (size_t)(bh * NCH + chunk) * (49 * 74);
#pragma unroll
    for (int dt = 0; dt < 5; ++dt) {
        int d = 16 * dt + c;
        if (d < 72) {
#pragma unroll
            for (int j = 0; j < 4; j++) {
                int agent = 16 * w + 4 * g + j;
                if (agent < 49) part[pbase + agent * 74 + d] = acc[dt][j];
            }
        }
    }
    if (g == 0) {
        int agent = 16 * w + c;
        if (agent < 49) {
            part[pbase + agent * 74 + 72] = m_run;
            part[pbase + agent * 74 + 73] = l_run;
        }
    }
}

// ---------- reduce partials across NCH chunks ----------
__global__ __launch_bounds__(256) void k_reduceA(const float* __restrict__ part, float* __restrict__ agv) {
    const int bh = blockIdx.x, t = threadIdx.x;
    const float* pb = part + (size_t)bh * NCH * (49 * 74);
    for (int idx = t; idx < 49 * 72; idx += 256) {
        int row = idx / 72, d = idx - row * 72;
        float m = -1e30f;
#pragma unroll
        for (int c = 0; c < NCH; c++) m = fmaxf(m, pb[c * (49 * 74) + row * 74 + 72]);
        float accv = 0.f, l = 0.f;
#pragma unroll
        for (int c = 0; c < NCH; c++) {
            const float* pc = pb + c * (49 * 74) + row * 74;
            float e = __expf(pc[72] - m);
            accv += pc[d] * e;
            l += pc[73] * e;
        }
        agv[(size_t)(bh * 49 + row) * 72 + d] = accv / l;
    }
}

// ---------- stage B: per-token softmax over 49 agents + PV, bf16 output ----------
__global__ __launch_bounds__(256) void k_stageB(const u16* __restrict__ Qp, const float* __restrict__ a_f,
                                                const float* __restrict__ agent_v, const float* __restrict__ bias2,
                                                u16* __restrict__ outatt) {
    const int t = threadIdx.x;
    const int bh = blockIdx.y; const int b = bh >> 3, h = bh & 7;
    __shared__ float a_s[49][72];
    __shared__ float av[49][72];
    for (int idx = t; idx < 49 * 72; idx += 256) {
        int ag = idx / 72, dd = idx % 72;
        a_s[ag][dd] = a_f[(size_t)(b * AGN + ag) * CC + h * HD + dd] * SCALE;
        av[ag][dd]  = agent_v[(size_t)(bh * AGN + ag) * HD + dd];
    }
    __syncthreads();
    const int n = blockIdx.x * 256 + t;
    if (n >= NN) return;
    const u16* qp = Qp + ((size_t)(b * 8 + h) * NN + n) * 72;
    const float* brow = bias2 + ((size_t)h * NN + n) * AGN;
    float s[49];
#pragma unroll
    for (int ag = 0; ag < 49; ++ag) s[ag] = brow[ag];
    for (int ch = 0; ch < 9; ++ch) {
        u16x8 qc = *(const u16x8*)(qp + ch * 8);
        float qf[8];
#pragma unroll
        for (int j = 0; j < 8; j++) qf[j] = bf2f(qc[j]);
#pragma unroll
        for (int ag = 0; ag < 49; ++ag) {
            float a2 = s[ag];
#pragma unroll
            for (int j = 0; j < 8; j++) a2 += qf[j] * a_s[ag][ch * 8 + j];
            s[ag] = a2;
        }
    }
    float mx = -1e30f;
#pragma unroll
    for (int ag = 0; ag < 49; ++ag) mx = fmaxf(mx, s[ag]);
    float l = 0.f;
#pragma unroll
    for (int ag = 0; ag < 49; ++ag) { float p = __expf(s[ag] - mx); s[ag] = p; l += p; }
    float inv = 1.f / l;
#pragma unroll
    for (int ag = 0; ag < 49; ++ag) s[ag] *= inv;
    u16* op = outatt + (size_t)(b * NN + n) * CC + h * HD;
    for (int dc = 0; dc < 9; ++dc) {
        float o8[8] = {0.f, 0.f, 0.f, 0.f, 0.f, 0.f, 0.f, 0.f};
#pragma unroll
        for (int ag = 0; ag < 49; ++ag)
#pragma unroll
            for (int j = 0; j < 8; j++) o8[j] += s[ag] * av[ag][dc * 8 + j];
        u16x8 rr;
#pragma unroll
        for (int j = 0; j < 8; j++) rr[j] = f2bf(o8[j]);
        *(u16x8*)(op + dc * 8) = rr;
    }
}

// ---------- depthwise 3x3 conv + affine + relu + add (reg-resident weights) ----------
__global__ __launch_bounds__(576) void k_conv(const u16* __restrict__ Vp, const u16* __restrict__ oat,
                                              const float* __restrict__ w, const float* __restrict__ gamma,
                                              const float* __restrict__ beta, u16* __restrict__ pre) {
    const int t = threadIdx.x;
    const int g8 = t % 72;                               // channel-group (8 ch)
    const int p  = t / 72;                               // 0..7
    const int c0 = g8 * 8;
    const int hh = c0 / 72, dl = c0 - hh * 72;

    __shared__ float wlds[CC * 9];                       // 20736 B
    __shared__ float glds[CC], blds[CC];                 //  4608 B
    for (int i = t; i < CC * 9; i += 576) wlds[i] = w[i];
    glds[t < CC ? t : 0] = gamma[t < CC ? t : 0];
    blds[t < CC ? t : 0] = beta[t < CC ? t : 0];
    __syncthreads();

    float wv[8][9], gm[8], bt[8];
#pragma unroll
    for (int j = 0; j < 8; j++) {
#pragma unroll
        for (int tap = 0; tap < 9; tap++) wv[j][tap] = wlds[(c0 + j) * 9 + tap];
        gm[j] = glds[c0 + j]; bt[j] = blds[c0 + j];
    }

    for (int pt = blockIdx.x * 8 + p; pt < BB * NN; pt += gridDim.x * 8) {
        int b = pt / NN, n = pt - b * NN;
        int y = n / 56, x = n % 56;
        const u16* vbase = Vp + ((size_t)(b * 8 + hh) * NN) * 72 + dl;
        float a[8] = {0.f, 0.f, 0.f, 0.f, 0.f, 0.f, 0.f, 0.f};
#pragma unroll
        for (int dy = -1; dy <= 1; ++dy) {
            int yy = y + dy; if (yy < 0 || yy > 55) continue;
#pragma unroll
            for (int dx = -1; dx <= 1; ++dx) {
                int xx = x + dx; if (xx < 0 || xx > 55) continue;
                u16x8 vv = *(const u16x8*)(vbase + (size_t)(yy * 56 + xx) * 72);
                int tap = (dy + 1) * 3 + (dx + 1);
#pragma unroll
                for (int j = 0; j < 8; j++) a[j] += bf2f(vv[j]) * wv[j][tap];
            }
        }
        u16x8 ov = *(const u16x8*)(oat + (size_t)pt * CC + c0);
        u16x8 rr;
#pragma unroll
        for (int j = 0; j < 8; j++)
            rr[j] = f2bf(bf2f(ov[j]) + fmaxf(a[j] * gm[j] + bt[j], 0.f));
        *(u16x8*)(pre + (size_t)pt * CC + c0) = rr;
    }
}

// ---------- launch ----------
extern "C" void kernel_launch(void* const* d_in, const int* in_sizes, int n_in,
                              void* d_out, int out_size, void* d_ws, size_t ws_size,
                              hipStream_t stream) {
    const float* x     = (const float*)d_in[0];
    const float* Wq    = (const float*)d_in[1];
    const float* Wkv   = (const float*)d_in[2];
    const float* an_b  = (const float*)d_in[3];
    const float* na_b  = (const float*)d_in[4];
    const float* ah_b  = (const float*)d_in[5];
    const float* aw_b  = (const float*)d_in[6];
    const float* ha_b  = (const float*)d_in[7];
    const float* wa_b  = (const float*)d_in[8];
    const float* dwcw  = (const float*)d_in[9];
    const float* gam   = (const float*)d_in[10];
    const float* bet   = (const float*)d_in[11];
    const float* projw = (const float*)d_in[12];
    const float* projb = (const float*)d_in[13];
    float* out = (float*)d_out;

    char* ws = (char*)d_ws;
    u16* wbT  = (u16*)(ws + 0);                          //  1,990,656
    u16* wpT  = (u16*)(ws + 1990656);                    //    663,552
    u16* xb   = (u16*)(ws + 2654208);                    // 57,802,752 (reused: stageA partials, then 'pre')
    u16* Qp   = (u16*)(ws + 60456960);                   // 57,802,752
    u16* Kp   = (u16*)(ws + 118259712);                  // 57,802,752 (reused as bf16 outatt after stageA)
    u16* Vp   = (u16*)(ws + 176062464);                  // 57,802,752
    float* af = (float*)(ws + 233865216);                //  1,806,336
    float* agv= (float*)(ws + 235671552);                //  1,806,336
    float* b1 = (float*)(ws + 237477888);                //  4,917,248  [h][n][49]
    float* b2 = (float*)(ws + 242395136);                //  4,917,248
    float* part = (float*)xb;                            // 12,995,584 (inside xb region)
    u16* obuf = Kp;                                      // bf16 outatt reuses Kp

    k_cast_x<<<28224, 256, 0, stream>>>(x, xb);
    k_prep_w<<<5184, 256, 0, stream>>>(Wq, Wkv, projw, wbT, wpT);
    k_bias1<<<4802, 256, 0, stream>>>(an_b, ah_b, aw_b, b1);
    k_bias2<<<4802, 256, 0, stream>>>(na_b, ha_b, wa_b, b2);
    k_gemm<0><<<dim3(14, 392), 256, 0, stream>>>(xb, wbT, Qp, Kp, Vp, nullptr, nullptr);
    k_pool<<<1764, 256, 0, stream>>>(Qp, af);
    k_stageA<<<dim3(NCH, 128), 256, 0, stream>>>(Kp, Vp, af, b1, part);
    k_reduceA<<<128, 256, 0, stream>>>(part, agv);
    k_stageB<<<dim3(13, 128), 256, 0, stream>>>(Qp, af, agv, b2, obuf);
    k_conv<<<784, 576, 0, stream>>>(Vp, obuf, dwcw, gam, bet, xb /*pre*/);
    k_gemm<1><<<dim3(5, 392), 256, 0, stream>>>(xb /*pre*/, wpT, nullptr, nullptr, nullptr, out, projb);
}

// Round 6
// 558.977 us; speedup vs baseline: 2.5444x; 1.1226x over previous
//
#include <hip/hip_runtime.h>
#include <stdint.h>

// ---------- types ----------
typedef unsigned short u16;
typedef u16   u16x4 __attribute__((ext_vector_type(4)));
typedef u16   u16x8 __attribute__((ext_vector_type(8)));
typedef float f32x4 __attribute__((ext_vector_type(4)));
typedef __bf16 bf16x8 __attribute__((ext_vector_type(8)));

// ---------- constants ----------
#define BB    16
#define NN    3136
#define CC    576
#define HEADS 8
#define HD    72
#define AGN   49
#define NTOT  1728
#define NCH   7                      // stageA chunks (448 tokens, 7 tiles of 64)
#define SCALE 0.1178511301977579f   // 72^-0.5

__device__ __forceinline__ u16 f2bf(float f) {
    unsigned u = __float_as_uint(f);
    return (u16)((u + 0x7fffu + ((u >> 16) & 1u)) >> 16);
}
__device__ __forceinline__ float bf2f(u16 u) {
    return __uint_as_float(((unsigned)u) << 16);
}

// ---------- cast x -> bf16 ----------
__global__ __launch_bounds__(256) void k_cast_x(const float* __restrict__ x, u16* __restrict__ xb) {
    size_t i = (size_t)blockIdx.x * 256 + threadIdx.x;
    f32x4 v = *(const f32x4*)(x + i * 4);
    u16x4 o; o[0] = f2bf(v[0]); o[1] = f2bf(v[1]); o[2] = f2bf(v[2]); o[3] = f2bf(v[3]);
    *(u16x4*)(xb + i * 4) = o;
}

// ---------- pack transposed bf16 weights ----------
__global__ __launch_bounds__(256) void k_prep_w(const float* __restrict__ Wq, const float* __restrict__ Wkv,
                                                const float* __restrict__ Wp,
                                                u16* __restrict__ wbT, u16* __restrict__ wpT) {
    int idx = blockIdx.x * 256 + threadIdx.x;
    if (idx < NTOT * CC) {
        int nn = idx / CC, kk = idx % CC;
        float v = (nn < CC) ? Wq[kk * CC + nn] : Wkv[kk * (2 * CC) + (nn - CC)];
        wbT[idx] = f2bf(v);
    } else {
        int j = idx - NTOT * CC;
        int nn = j / CC, kk = j % CC;
        wpT[j] = f2bf(Wp[kk * CC + nn]);
    }
}

// ---------- jax.image.resize 'linear' 7x7 -> 56x56 ----------
__device__ __forceinline__ float bilerp7(const float* __restrict__ g, int oy, int ox) {
    float cy = (oy - 3.5f) * 0.125f;
    float cx = (ox - 3.5f) * 0.125f;
    float fy0 = floorf(cy), fx0 = floorf(cx);
    float ty = cy - fy0, tx = cx - fx0;
    int iy0 = (int)fy0, ix0 = (int)fx0;
    int y0 = min(6, max(0, iy0)), y1 = min(6, max(0, iy0 + 1));
    int x0 = min(6, max(0, ix0)), x1 = min(6, max(0, ix0 + 1));
    float g00 = g[y0 * 7 + x0], g01 = g[y0 * 7 + x1];
    float g10 = g[y1 * 7 + x0], g11 = g[y1 * 7 + x1];
    return (1.f - ty) * ((1.f - tx) * g00 + tx * g01) + ty * ((1.f - tx) * g10 + tx * g11);
}

// bias1 layout: [h][n][49]
__global__ __launch_bounds__(256) void k_bias1(const float* __restrict__ an, const float* __restrict__ ah,
                                               const float* __restrict__ aw, float* __restrict__ b1) {
    int idx = blockIdx.x * 256 + threadIdx.x;
    int ag = idx % AGN; int r = idx / AGN; int n = r % NN; int h = r / NN;
    int y = n / 56, x = n % 56;
    float v = bilerp7(an + (h * AGN + ag) * 49, y, x);
    b1[idx] = v + ah[(h * AGN + ag) * 56 + y] + aw[(h * AGN + ag) * 56 + x];
}

// bias2 layout: [h][n][64] f32, pad ag>=49 with -1e30 (softmax kills them)
__global__ __launch_bounds__(256) void k_bias2(const float* __restrict__ na, const float* __restrict__ ha,
                                               const float* __restrict__ wa, float* __restrict__ b2p) {
    int idx = blockIdx.x * 256 + threadIdx.x;            // 8*3136*64
    int ag = idx & 63; int r = idx >> 6; int n = r % NN; int h = r / NN;
    float v;
    if (ag < AGN) {
        int y = n / 56, x = n % 56;
        v = bilerp7(na + (h * AGN + ag) * 49, y, x)
          + ha[(h * 56 + y) * AGN + ag] + wa[(h * 56 + x) * AGN + ag];
    } else v = -1e30f;
    b2p[idx] = v;
}

// ---------- MFMA GEMM: A[M x 576] @ Bt[NB x 576]^T,  BM=128 BN=128 BK=64, XCD-swizzled ----------
// MODE 0: scatter bf16 to Qp/Kp/Vp (NB=1728); MODE 1: f32+bias to Cf (NB=576); MODE 2: f32 to Cf (NB=576)
template<int MODE>
__global__ __launch_bounds__(256) void k_gemm(const u16* __restrict__ A, const u16* __restrict__ Bt,
                                              u16* __restrict__ Qp, u16* __restrict__ Kp, u16* __restrict__ Vp,
                                              float* __restrict__ Cf, const float* __restrict__ bias,
                                              const int M) {
    const int NB = (MODE == 0) ? NTOT : CC;
    __shared__ u16 Asm[128 * 64];
    __shared__ u16 Bsm[128 * 64];
    const int t = threadIdx.x, lane = t & 63, wid = t >> 6;
    const int wm = wid & 1, wn = wid >> 1;
    // bijective XCD swizzle (m204): contiguous tile-ids per XCD
    const int nwg = gridDim.x * gridDim.y;
    const int id = blockIdx.y * gridDim.x + blockIdx.x;
    const int qq = nwg >> 3, rr = nwg & 7;
    const int xcd = id & 7, off = id >> 3;
    const int nid = (xcd < rr ? xcd * (qq + 1) : rr * (qq + 1) + (xcd - rr) * qq) + off;
    const int row0 = (nid / gridDim.x) * 128, col0 = (nid % gridDim.x) * 128;
    const int lr = lane & 15, lk = lane >> 4;
    f32x4 acc[4][4];
#pragma unroll
    for (int m = 0; m < 4; m++)
#pragma unroll
        for (int n2 = 0; n2 < 4; n2++) acc[m][n2] = (f32x4)0.f;

    for (int kt = 0; kt < 9; ++kt) {
        const int k0 = kt * 64;
#pragma unroll
        for (int it = 0; it < 4; ++it) {
            int flat = it * 256 + wid * 64 + lane;
            int r = flat >> 3, lc = (flat & 7) ^ (r & 7);
            int arow = min(row0 + r, M - 1);
            const u16* src = A + (size_t)arow * CC + k0 + lc * 8;
            __builtin_amdgcn_global_load_lds((const __attribute__((address_space(1))) void*)src,
                                             (__attribute__((address_space(3))) void*)(&Asm[(it * 256 + wid * 64) * 8]),
                                             16, 0, 0);
        }
#pragma unroll
        for (int it = 0; it < 4; ++it) {
            int flat = it * 256 + wid * 64 + lane;
            int r = flat >> 3, lc = (flat & 7) ^ (r & 7);
            int brow = min(col0 + r, NB - 1);
            const u16* src = Bt + (size_t)brow * CC + k0 + lc * 8;
            __builtin_amdgcn_global_load_lds((const __attribute__((address_space(1))) void*)src,
                                             (__attribute__((address_space(3))) void*)(&Bsm[(it * 256 + wid * 64) * 8]),
                                             16, 0, 0);
        }
        __syncthreads();
#pragma unroll
        for (int kk = 0; kk < 2; ++kk) {
            const int klocal2 = (kk * 32 + lk * 8) * 2;
            bf16x8 av[4], bv[4];
#pragma unroll
            for (int m = 0; m < 4; m++) {
                int row = wm * 64 + m * 16 + lr;
                av[m] = *(const bf16x8*)((const char*)Asm + row * 128 + (klocal2 ^ ((row & 7) << 4)));
            }
#pragma unroll
            for (int n2 = 0; n2 < 4; n2++) {
                int row = wn * 64 + n2 * 16 + lr;
                bv[n2] = *(const bf16x8*)((const char*)Bsm + row * 128 + (klocal2 ^ ((row & 7) << 4)));
            }
#pragma unroll
            for (int m = 0; m < 4; m++)
#pragma unroll
                for (int n2 = 0; n2 < 4; n2++)
                    acc[m][n2] = __builtin_amdgcn_mfma_f32_16x16x32_bf16(av[m], bv[n2], acc[m][n2], 0, 0, 0);
        }
        __syncthreads();
    }
#pragma unroll
    for (int n2 = 0; n2 < 4; n2++) {
        int cgl = col0 + wn * 64 + n2 * 16 + lr;
        if (cgl >= NB) continue;
        if (MODE == 0) {
            int which = cgl / 576;
            int rem = cgl - which * 576;
            int hh = rem / 72;
            int dd = rem - hh * 72;
            u16* dst = which == 0 ? Qp : (which == 1 ? Kp : Vp);
#pragma unroll
            for (int m = 0; m < 4; m++)
#pragma unroll
                for (int j = 0; j < 4; j++) {
                    int rgl = row0 + wm * 64 + m * 16 + lk * 4 + j;
                    int b = rgl / NN, n = rgl - b * NN;
                    dst[((size_t)(b * 8 + hh) * NN + n) * 72 + dd] = f2bf(acc[m][n2][j]);
                }
        } else {
            float addv = (MODE == 1) ? bias[cgl] : 0.f;
#pragma unroll
            for (int m = 0; m < 4; m++)
#pragma unroll
                for (int j = 0; j < 4; j++) {
                    int rgl = row0 + wm * 64 + m * 16 + lk * 4 + j;
                    if (rgl < M) Cf[(size_t)rgl * 576 + cgl] = acc[m][n2][j] + addv;
                }
        }
    }
}

// ---------- pool x (8x8 windows) -> px[b*49+ag][576] bf16;  pool(x)@Wq == pool(x@Wq) ----------
__global__ __launch_bounds__(256) void k_poolx(const u16* __restrict__ xb, u16* __restrict__ px) {
    const int t = threadIdx.x;
    const int b = blockIdx.x / 7, p1 = blockIdx.x % 7;
    for (int task = t; task < 504; task += 256) {
        int p2 = task / 72, c8 = task - p2 * 72;
        const u16* base = xb + ((size_t)b * NN + (p1 * 8) * 56 + p2 * 8) * CC + c8 * 8;
        float s[8] = {0.f, 0.f, 0.f, 0.f, 0.f, 0.f, 0.f, 0.f};
        for (int y = 0; y < 8; ++y)
#pragma unroll
            for (int x = 0; x < 8; ++x) {
                u16x8 v = *(const u16x8*)(base + (size_t)(y * 56 + x) * CC);
#pragma unroll
                for (int j = 0; j < 8; j++) s[j] += bf2f(v[j]);
            }
        u16x8 o;
#pragma unroll
        for (int j = 0; j < 8; j++) o[j] = f2bf(s[j] * 0.015625f);
        *(u16x8*)(px + (size_t)(b * AGN + p1 * 7 + p2) * CC + c8 * 8) = o;
    }
}

// ---------- stage A (MFMA): S^T = mfma(K, a), online softmax per agent-col, PV = mfma(P, V^T) ----------
__global__ __launch_bounds__(256) void k_stageA(const u16* __restrict__ Kp, const u16* __restrict__ Vp,
                                                const float* __restrict__ a_f, const float* __restrict__ b1,
                                                float* __restrict__ part) {
    const int t = threadIdx.x, lane = t & 63, w = t >> 6;
    const int c = lane & 15, g = lane >> 4;
    const int bh = blockIdx.y, b = bh >> 3, h = bh & 7;
    const int chunk = blockIdx.x;                        // 0..6

    __shared__ u16 A_lds[64][104];
    __shared__ u16 K_lds[64][104];
    __shared__ u16 Vt[80][72];
    __shared__ u16 P_lds[64][72];

    for (int i = t; i < 64 * 104; i += 256) {
        int r = i / 104, cc = i - r * 104;
        if (cc >= 72 || r >= 49) A_lds[r][cc] = 0;
        if (cc >= 72) K_lds[r][cc] = 0;
    }
    for (int i = t; i < 8 * 72; i += 256) Vt[72 + i / 72][i % 72] = 0;
    for (int i = t; i < 49 * 72; i += 256) {
        int r = i / 72, d = i - r * 72;
        A_lds[r][d] = f2bf(a_f[(size_t)(b * 49 + r) * CC + h * 72 + d] * SCALE);
    }
    __syncthreads();

    bf16x8 bfA[3];
#pragma unroll
    for (int ks = 0; ks < 3; ++ks) bfA[ks] = *(const bf16x8*)&A_lds[16 * w + c][8 * g + 32 * ks];

    float m_run = -1e30f, l_run = 0.f;
    f32x4 acc[5];
#pragma unroll
    for (int dt = 0; dt < 5; ++dt) acc[dt] = (f32x4)0.f;

    const u16* kb = Kp + ((size_t)(b * 8 + h) * NN + chunk * 448) * 72;
    const u16* vb = Vp + ((size_t)(b * 8 + h) * NN + chunk * 448) * 72;
    const int arow = min(16 * w + c, 48);

    for (int tile = 0; tile < 7; ++tile) {
        for (int i = t; i < 576; i += 256) {
            int nl = i / 9, ch = i - nl * 9;
            u16x8 kd = *(const u16x8*)(kb + (size_t)tile * 4608 + i * 8);
            *(u16x8*)&K_lds[nl][ch * 8] = kd;
        }
        for (int i = t; i < 576; i += 256) {
            int ch = i >> 6, nl = i & 63;
            u16x8 vd = *(const u16x8*)(vb + (size_t)tile * 4608 + (nl * 9 + ch) * 8);
#pragma unroll
            for (int j = 0; j < 8; j++) Vt[ch * 8 + j][nl] = vd[j];
        }
        __syncthreads();

        f32x4 sT[4];
        const int nbase = chunk * 448 + tile * 64 + 4 * g;
#pragma unroll
        for (int nm = 0; nm < 4; ++nm) {
            f32x4 sv;
#pragma unroll
            for (int j = 0; j < 4; j++)
                sv[j] = b1[(size_t)(h * NN + nbase + 16 * nm + j) * AGN + arow];
#pragma unroll
            for (int ks = 0; ks < 3; ++ks) {
                bf16x8 af = *(const bf16x8*)&K_lds[16 * nm + c][8 * g + 32 * ks];
                sv = __builtin_amdgcn_mfma_f32_16x16x32_bf16(af, bfA[ks], sv, 0, 0, 0);
            }
            sT[nm] = sv;
        }

        float mt = sT[0][0];
#pragma unroll
        for (int nm = 0; nm < 4; ++nm)
#pragma unroll
            for (int j = 0; j < 4; j++) mt = fmaxf(mt, sT[nm][j]);
        mt = fmaxf(mt, __shfl_xor(mt, 16, 64));
        mt = fmaxf(mt, __shfl_xor(mt, 32, 64));
        float mnew = fmaxf(m_run, mt);
        float ps = 0.f;
#pragma unroll
        for (int nm = 0; nm < 4; ++nm) {
            float p0 = __expf(sT[nm][0] - mnew);
            float p1 = __expf(sT[nm][1] - mnew);
            float p2 = __expf(sT[nm][2] - mnew);
            float p3 = __expf(sT[nm][3] - mnew);
            ps += (p0 + p1) + (p2 + p3);
            unsigned pk01 = ((unsigned)f2bf(p1) << 16) | f2bf(p0);
            unsigned pk23 = ((unsigned)f2bf(p3) << 16) | f2bf(p2);
            unsigned* dst = (unsigned*)&P_lds[16 * w + c][16 * nm + 4 * g];
            dst[0] = pk01; dst[1] = pk23;
        }
        ps += __shfl_xor(ps, 16, 64);
        ps += __shfl_xor(ps, 32, 64);
        float rsc = __expf(m_run - mnew);
        l_run = l_run * rsc + ps;
        m_run = mnew;

        float rj[4];
#pragma unroll
        for (int j = 0; j < 4; j++) rj[j] = __shfl(rsc, 4 * g + j, 64);
        bf16x8 pa[2];
#pragma unroll
        for (int ks = 0; ks < 2; ++ks) pa[ks] = *(const bf16x8*)&P_lds[16 * w + c][8 * g + 32 * ks];
#pragma unroll
        for (int dt = 0; dt < 5; ++dt) {
            f32x4 a0 = acc[dt];
#pragma unroll
            for (int j = 0; j < 4; j++) a0[j] *= rj[j];
#pragma unroll
            for (int ks = 0; ks < 2; ++ks) {
                bf16x8 vf = *(const bf16x8*)&Vt[16 * dt + c][8 * g + 32 * ks];
                a0 = __builtin_amdgcn_mfma_f32_16x16x32_bf16(pa[ks], vf, a0, 0, 0, 0);
            }
            acc[dt] = a0;
        }
        __syncthreads();
    }

    const size_t pbase = (size_t)(bh * NCH + chunk) * (49 * 74);
#pragma unroll
    for (int dt = 0; dt < 5; ++dt) {
        int d = 16 * dt + c;
        if (d < 72) {
#pragma unroll
            for (int j = 0; j < 4; j++) {
                int agent = 16 * w + 4 * g + j;
                if (agent < 49) part[pbase + agent * 74 + d] = acc[dt][j];
            }
        }
    }
    if (g == 0) {
        int agent = 16 * w + c;
        if (agent < 49) {
            part[pbase + agent * 74 + 72] = m_run;
            part[pbase + agent * 74 + 73] = l_run;
        }
    }
}

// ---------- reduce partials across NCH chunks ----------
__global__ __launch_bounds__(256) void k_reduceA(const float* __restrict__ part, float* __restrict__ agv) {
    const int bh = blockIdx.x, t = threadIdx.x;
    const float* pb = part + (size_t)bh * NCH * (49 * 74);
    for (int idx = t; idx < 49 * 72; idx += 256) {
        int row = idx / 72, d = idx - row * 72;
        float m = -1e30f;
#pragma unroll
        for (int c = 0; c < NCH; c++) m = fmaxf(m, pb[c * (49 * 74) + row * 74 + 72]);
        float accv = 0.f, l = 0.f;
#pragma unroll
        for (int c = 0; c < NCH; c++) {
            const float* pc = pb + c * (49 * 74) + row * 74;
            float e = __expf(pc[72] - m);
            accv += pc[d] * e;
            l += pc[73] * e;
        }
        agv[(size_t)(bh * 49 + row) * 72 + d] = accv / l;
    }
}

// ---------- stage B (MFMA): S = mfma(agents, q) -> softmax over 49 -> PV = mfma(P^T, av^T) ----------
__global__ __launch_bounds__(256) void k_stageB(const u16* __restrict__ Qp, const float* __restrict__ a_f,
                                                const float* __restrict__ agv, const float* __restrict__ b2p,
                                                u16* __restrict__ oat) {
    const int t = threadIdx.x, lane = t & 63, w = t >> 6;
    const int c = lane & 15, g = lane >> 4;
    const int bh = blockIdx.y, b = bh >> 3, h = bh & 7;
    const int n0 = blockIdx.x * 256;

    __shared__ u16 A_lds[64][104];                       // agents (scaled bf16), ag>=49 & k>=72 zero
    __shared__ u16 avT[80][72];                          // [d][ag]: d pad 72..79 zero, ag pad 49..63 zero
    __shared__ u16 Pt[4][64][76];                        // per-wave P^T: [n-local][ag]

    for (int i = t; i < 64 * 104; i += 256) {
        int r = i / 104, cc = i - r * 104;
        if (cc >= 72 || r >= 49) A_lds[r][cc] = 0;
    }
    for (int i = t; i < 80 * 72; i += 256) ((u16*)avT)[i] = 0;
    __syncthreads();
    for (int i = t; i < 49 * 72; i += 256) {
        int r = i / 72, d = i - r * 72;
        A_lds[r][d] = f2bf(a_f[(size_t)(b * 49 + r) * CC + h * 72 + d] * SCALE);
        avT[d][r]   = f2bf(agv[(size_t)(bh * 49 + r) * 72 + d]);
    }
    __syncthreads();

    // hoisted agent A-frags (rows ag = 16mt + c)
    bf16x8 afr[4][3];
#pragma unroll
    for (int mt = 0; mt < 4; ++mt)
#pragma unroll
        for (int ks = 0; ks < 3; ++ks) afr[mt][ks] = *(const bf16x8*)&A_lds[16 * mt + c][8 * g + 32 * ks];

    const int nw0 = n0 + w * 64;
    // ---- QK + softmax (49 agents fit; no online state) ----
#pragma unroll
    for (int cg = 0; cg < 4; ++cg) {
        const int n = nw0 + 16 * cg + c;
        const int ne = min(n, NN - 1);
        const u16* qp = Qp + ((size_t)(b * 8 + h) * NN + ne) * 72;
        bf16x8 qf[3];
#pragma unroll
        for (int ks = 0; ks < 3; ++ks) qf[ks] = *(const bf16x8*)(qp + 8 * g + 32 * ks);  // k>=72 garbage x A-zero = 0
        const float* bp = b2p + (size_t)(h * NN + ne) * 64;
        f32x4 sv[4];
#pragma unroll
        for (int mt = 0; mt < 4; ++mt) sv[mt] = *(const f32x4*)(bp + 16 * mt + 4 * g);
#pragma unroll
        for (int ks = 0; ks < 3; ++ks)
#pragma unroll
            for (int mt = 0; mt < 4; ++mt)
                sv[mt] = __builtin_amdgcn_mfma_f32_16x16x32_bf16(afr[mt][ks], qf[ks], sv[mt], 0, 0, 0);
        // softmax over ag (16 in-lane + 2 hops over g)
        float mx = sv[0][0];
#pragma unroll
        for (int mt = 0; mt < 4; ++mt)
#pragma unroll
            for (int j = 0; j < 4; j++) mx = fmaxf(mx, sv[mt][j]);
        mx = fmaxf(mx, __shfl_xor(mx, 16, 64));
        mx = fmaxf(mx, __shfl_xor(mx, 32, 64));
        float ps = 0.f;
#pragma unroll
        for (int mt = 0; mt < 4; ++mt) {
#pragma unroll
            for (int j = 0; j < 4; j++) { sv[mt][j] = __expf(sv[mt][j] - mx); ps += sv[mt][j]; }
        }
        ps += __shfl_xor(ps, 16, 64);
        ps += __shfl_xor(ps, 32, 64);
        float inv = 1.f / ps;
#pragma unroll
        for (int mt = 0; mt < 4; ++mt) {
            unsigned pk01 = ((unsigned)f2bf(sv[mt][1] * inv) << 16) | f2bf(sv[mt][0] * inv);
            unsigned pk23 = ((unsigned)f2bf(sv[mt][3] * inv) << 16) | f2bf(sv[mt][2] * inv);
            unsigned* dst = (unsigned*)&Pt[w][16 * cg + c][16 * mt + 4 * g];
            dst[0] = pk01; dst[1] = pk23;
        }
    }
    // ---- PV (per-wave Pt, no barrier needed) ----
    bf16x8 vfr[5][2];
#pragma unroll
    for (int dt = 0; dt < 5; ++dt)
#pragma unroll
        for (int ks = 0; ks < 2; ++ks) vfr[dt][ks] = *(const bf16x8*)&avT[16 * dt + c][8 * g + 32 * ks];
#pragma unroll
    for (int rt = 0; rt < 4; ++rt) {
        bf16x8 pf[2];
#pragma unroll
        for (int ks = 0; ks < 2; ++ks) pf[ks] = *(const bf16x8*)&Pt[w][16 * rt + c][8 * g + 32 * ks];
#pragma unroll
        for (int dt = 0; dt < 5; ++dt) {
            f32x4 a0 = (f32x4)0.f;
            a0 = __builtin_amdgcn_mfma_f32_16x16x32_bf16(pf[0], vfr[dt][0], a0, 0, 0, 0);
            a0 = __builtin_amdgcn_mfma_f32_16x16x32_bf16(pf[1], vfr[dt][1], a0, 0, 0, 0);
            int dd = 16 * dt + c;
            if (dd < 72) {
#pragma unroll
                for (int j = 0; j < 4; j++) {
                    int nn2 = nw0 + 16 * rt + 4 * g + j;
                    if (nn2 < NN) oat[((size_t)b * NN + nn2) * CC + h * 72 + dd] = f2bf(a0[j]);
                }
            }
        }
    }
}

// ---------- depthwise 3x3 conv + affine + relu + add (reg-resident weights) ----------
__global__ __launch_bounds__(576) void k_conv(const u16* __restrict__ Vp, const u16* __restrict__ oat,
                                              const float* __restrict__ w, const float* __restrict__ gamma,
                                              const float* __restrict__ beta, u16* __restrict__ pre) {
    const int t = threadIdx.x;
    const int g8 = t % 72;
    const int p  = t / 72;
    const int c0 = g8 * 8;
    const int hh = c0 / 72, dl = c0 - hh * 72;

    __shared__ float wlds[CC * 9];
    __shared__ float glds[CC], blds[CC];
    for (int i = t; i < CC * 9; i += 576) wlds[i] = w[i];
    glds[t < CC ? t : 0] = gamma[t < CC ? t : 0];
    blds[t < CC ? t : 0] = beta[t < CC ? t : 0];
    __syncthreads();

    float wv[8][9], gm[8], bt[8];
#pragma unroll
    for (int j = 0; j < 8; j++) {
#pragma unroll
        for (int tap = 0; tap < 9; tap++) wv[j][tap] = wlds[(c0 + j) * 9 + tap];
        gm[j] = glds[c0 + j]; bt[j] = blds[c0 + j];
    }

    for (int pt = blockIdx.x * 8 + p; pt < BB * NN; pt += gridDim.x * 8) {
        int b = pt / NN, n = pt - b * NN;
        int y = n / 56, x = n % 56;
        const u16* vbase = Vp + ((size_t)(b * 8 + hh) * NN) * 72 + dl;
        float a[8] = {0.f, 0.f, 0.f, 0.f, 0.f, 0.f, 0.f, 0.f};
#pragma unroll
        for (int dy = -1; dy <= 1; ++dy) {
            int yy = y + dy; if (yy < 0 || yy > 55) continue;
#pragma unroll
            for (int dx = -1; dx <= 1; ++dx) {
                int xx = x + dx; if (xx < 0 || xx > 55) continue;
                u16x8 vv = *(const u16x8*)(vbase + (size_t)(yy * 56 + xx) * 72);
                int tap = (dy + 1) * 3 + (dx + 1);
#pragma unroll
                for (int j = 0; j < 8; j++) a[j] += bf2f(vv[j]) * wv[j][tap];
            }
        }
        u16x8 ov = *(const u16x8*)(oat + (size_t)pt * CC + c0);
        u16x8 rr;
#pragma unroll
        for (int j = 0; j < 8; j++)
            rr[j] = f2bf(bf2f(ov[j]) + fmaxf(a[j] * gm[j] + bt[j], 0.f));
        *(u16x8*)(pre + (size_t)pt * CC + c0) = rr;
    }
}

// ---------- launch ----------
extern "C" void kernel_launch(void* const* d_in, const int* in_sizes, int n_in,
                              void* d_out, int out_size, void* d_ws, size_t ws_size,
                              hipStream_t stream) {
    const float* x     = (const float*)d_in[0];
    const float* Wq    = (const float*)d_in[1];
    const float* Wkv   = (const float*)d_in[2];
    const float* an_b  = (const float*)d_in[3];
    const float* na_b  = (const float*)d_in[4];
    const float* ah_b  = (const float*)d_in[5];
    const float* aw_b  = (const float*)d_in[6];
    const float* ha_b  = (const float*)d_in[7];
    const float* wa_b  = (const float*)d_in[8];
    const float* dwcw  = (const float*)d_in[9];
    const float* gam   = (const float*)d_in[10];
    const float* bet   = (const float*)d_in[11];
    const float* projw = (const float*)d_in[12];
    const float* projb = (const float*)d_in[13];
    float* out = (float*)d_out;

    char* ws = (char*)d_ws;
    u16* wbT  = (u16*)(ws + 0);                          //  1,990,656
    u16* wpT  = (u16*)(ws + 1990656);                    //    663,552
    u16* xb   = (u16*)(ws + 2654208);                    // 57,802,752 (reused: stageA partials, then 'pre')
    u16* Qp   = (u16*)(ws + 60456960);                   // 57,802,752
    u16* Kp   = (u16*)(ws + 118259712);                  // 57,802,752 (reused as bf16 outatt after stageA)
    u16* Vp   = (u16*)(ws + 176062464);                  // 57,802,752
    float* af = (float*)(ws + 233865216);                //  1,806,336
    u16* px   = (u16*)(ws + 235671552);                  //    903,168 (agv region: disjoint lifetime)
    float* agv= (float*)(ws + 235671552);                //  1,806,336
    float* b1 = (float*)(ws + 237477888);                //  4,917,248  [h][n][49]
    float* b2p= (float*)(ws + 242395136);                //  6,422,528  [h][n][64] padded
    float* part = (float*)xb;                            // 12,995,584 (inside xb region)
    u16* obuf = Kp;

    k_cast_x<<<28224, 256, 0, stream>>>(x, xb);
    k_prep_w<<<5184, 256, 0, stream>>>(Wq, Wkv, projw, wbT, wpT);
    k_bias1<<<4802, 256, 0, stream>>>(an_b, ah_b, aw_b, b1);
    k_bias2<<<6272, 256, 0, stream>>>(na_b, ha_b, wa_b, b2p);
    k_poolx<<<112, 256, 0, stream>>>(xb, px);
    k_gemm<2><<<dim3(5, 7), 256, 0, stream>>>(px, wbT, nullptr, nullptr, nullptr, af, nullptr, 784);
    k_gemm<0><<<dim3(14, 392), 256, 0, stream>>>(xb, wbT, Qp, Kp, Vp, nullptr, nullptr, BB * NN);
    k_stageA<<<dim3(NCH, 128), 256, 0, stream>>>(Kp, Vp, af, b1, part);
    k_reduceA<<<128, 256, 0, stream>>>(part, agv);
    k_stageB<<<dim3(13, 128), 256, 0, stream>>>(Qp, af, agv, b2p, obuf);
    k_conv<<<784, 576, 0, stream>>>(Vp, obuf, dwcw, gam, bet, xb /*pre*/);
    k_gemm<1><<<dim3(5, 392), 256, 0, stream>>>(xb /*pre*/, wpT, nullptr, nullptr, nullptr, out, projb, BB * NN);
}

// Round 7
// 552.048 us; speedup vs baseline: 2.5763x; 1.0126x over previous
//
#include <hip/hip_runtime.h>
#include <stdint.h>

// ---------- types ----------
typedef unsigned short u16;
typedef u16   u16x4 __attribute__((ext_vector_type(4)));
typedef u16   u16x8 __attribute__((ext_vector_type(8)));
typedef float f32x4 __attribute__((ext_vector_type(4)));
typedef __bf16 bf16x8 __attribute__((ext_vector_type(8)));

// ---------- constants ----------
#define BB    16
#define NN    3136
#define CC    576
#define HEADS 8
#define HD    72
#define AGN   49
#define NTOT  1728
#define NCH   7                      // stageA chunks (448 tokens, 7 tiles of 64)
#define SCALE 0.1178511301977579f   // 72^-0.5

__device__ __forceinline__ u16 f2bf(float f) {
    unsigned u = __float_as_uint(f);
    return (u16)((u + 0x7fffu + ((u >> 16) & 1u)) >> 16);
}
__device__ __forceinline__ float bf2f(u16 u) {
    return __uint_as_float(((unsigned)u) << 16);
}

// ---------- cast x -> bf16 ----------
__global__ __launch_bounds__(256) void k_cast_x(const float* __restrict__ x, u16* __restrict__ xb) {
    size_t i = (size_t)blockIdx.x * 256 + threadIdx.x;
    f32x4 v = *(const f32x4*)(x + i * 4);
    u16x4 o; o[0] = f2bf(v[0]); o[1] = f2bf(v[1]); o[2] = f2bf(v[2]); o[3] = f2bf(v[3]);
    *(u16x4*)(xb + i * 4) = o;
}

// ---------- pack transposed bf16 weights ----------
__global__ __launch_bounds__(256) void k_prep_w(const float* __restrict__ Wq, const float* __restrict__ Wkv,
                                                const float* __restrict__ Wp,
                                                u16* __restrict__ wbT, u16* __restrict__ wpT) {
    int idx = blockIdx.x * 256 + threadIdx.x;
    if (idx < NTOT * CC) {
        int nn = idx / CC, kk = idx % CC;
        float v = (nn < CC) ? Wq[kk * CC + nn] : Wkv[kk * (2 * CC) + (nn - CC)];
        wbT[idx] = f2bf(v);
    } else {
        int j = idx - NTOT * CC;
        int nn = j / CC, kk = j % CC;
        wpT[j] = f2bf(Wp[kk * CC + nn]);
    }
}

// ---------- jax.image.resize 'linear' 7x7 -> 56x56 ----------
__device__ __forceinline__ float bilerp7(const float* __restrict__ g, int oy, int ox) {
    float cy = (oy - 3.5f) * 0.125f;
    float cx = (ox - 3.5f) * 0.125f;
    float fy0 = floorf(cy), fx0 = floorf(cx);
    float ty = cy - fy0, tx = cx - fx0;
    int iy0 = (int)fy0, ix0 = (int)fx0;
    int y0 = min(6, max(0, iy0)), y1 = min(6, max(0, iy0 + 1));
    int x0 = min(6, max(0, ix0)), x1 = min(6, max(0, ix0 + 1));
    float g00 = g[y0 * 7 + x0], g01 = g[y0 * 7 + x1];
    float g10 = g[y1 * 7 + x0], g11 = g[y1 * 7 + x1];
    return (1.f - ty) * ((1.f - tx) * g00 + tx * g01) + ty * ((1.f - tx) * g10 + tx * g11);
}

// bias1 layout: [h][n][49]
__global__ __launch_bounds__(256) void k_bias1(const float* __restrict__ an, const float* __restrict__ ah,
                                               const float* __restrict__ aw, float* __restrict__ b1) {
    int idx = blockIdx.x * 256 + threadIdx.x;
    int ag = idx % AGN; int r = idx / AGN; int n = r % NN; int h = r / NN;
    int y = n / 56, x = n % 56;
    float v = bilerp7(an + (h * AGN + ag) * 49, y, x);
    b1[idx] = v + ah[(h * AGN + ag) * 56 + y] + aw[(h * AGN + ag) * 56 + x];
}

// bias2 layout: [h][n][64] f32, pad ag>=49 with -1e30 (softmax kills them)
__global__ __launch_bounds__(256) void k_bias2(const float* __restrict__ na, const float* __restrict__ ha,
                                               const float* __restrict__ wa, float* __restrict__ b2p) {
    int idx = blockIdx.x * 256 + threadIdx.x;
    int ag = idx & 63; int r = idx >> 6; int n = r % NN; int h = r / NN;
    float v;
    if (ag < AGN) {
        int y = n / 56, x = n % 56;
        v = bilerp7(na + (h * AGN + ag) * 49, y, x)
          + ha[(h * 56 + y) * AGN + ag] + wa[(h * 56 + x) * AGN + ag];
    } else v = -1e30f;
    b2p[idx] = v;
}

// ---------- MFMA GEMM: A[M x 576] @ Bt[NB x 576]^T,  BM=128 BN=128 BK=64, XCD-swizzled ----------
// MODE 0: bf16 to Qp/Kp/Vp (NB=1728); MODE 1: f32+bias to Cf (NB=576); MODE 2: f32 to Cf (NB=576)
// Epilogue goes through the (dead) staging LDS for fully-coalesced stores.
template<int MODE>
__global__ __launch_bounds__(256) void k_gemm(const u16* __restrict__ A, const u16* __restrict__ Bt,
                                              u16* __restrict__ Qp, u16* __restrict__ Kp, u16* __restrict__ Vp,
                                              float* __restrict__ Cf, const float* __restrict__ bias,
                                              const int M) {
    const int NB = (MODE == 0) ? NTOT : CC;
    __shared__ u16 SMEM[2 * 128 * 64];                   // 32 KB: Asm | Bsm, reused by epilogue
    u16* Asm = SMEM;
    u16* Bsm = SMEM + 128 * 64;
    const int t = threadIdx.x, lane = t & 63, wid = t >> 6;
    const int wm = wid & 1, wn = wid >> 1;
    // bijective XCD swizzle (m204)
    const int nwg = gridDim.x * gridDim.y;
    const int id = blockIdx.y * gridDim.x + blockIdx.x;
    const int qq = nwg >> 3, rr = nwg & 7;
    const int xcd = id & 7, off = id >> 3;
    const int nid = (xcd < rr ? xcd * (qq + 1) : rr * (qq + 1) + (xcd - rr) * qq) + off;
    const int row0 = (nid / gridDim.x) * 128, col0 = (nid % gridDim.x) * 128;
    const int lr = lane & 15, lk = lane >> 4;
    f32x4 acc[4][4];
#pragma unroll
    for (int m = 0; m < 4; m++)
#pragma unroll
        for (int n2 = 0; n2 < 4; n2++) acc[m][n2] = (f32x4)0.f;

    for (int kt = 0; kt < 9; ++kt) {
        const int k0 = kt * 64;
#pragma unroll
        for (int it = 0; it < 4; ++it) {
            int flat = it * 256 + wid * 64 + lane;
            int r = flat >> 3, lc = (flat & 7) ^ (r & 7);
            int arow = (MODE == 0) ? (row0 + r) : min(row0 + r, M - 1);
            const u16* src = A + (size_t)arow * CC + k0 + lc * 8;
            __builtin_amdgcn_global_load_lds((const __attribute__((address_space(1))) void*)src,
                                             (__attribute__((address_space(3))) void*)(&Asm[(it * 256 + wid * 64) * 8]),
                                             16, 0, 0);
        }
#pragma unroll
        for (int it = 0; it < 4; ++it) {
            int flat = it * 256 + wid * 64 + lane;
            int r = flat >> 3, lc = (flat & 7) ^ (r & 7);
            int brow = min(col0 + r, NB - 1);
            const u16* src = Bt + (size_t)brow * CC + k0 + lc * 8;
            __builtin_amdgcn_global_load_lds((const __attribute__((address_space(1))) void*)src,
                                             (__attribute__((address_space(3))) void*)(&Bsm[(it * 256 + wid * 64) * 8]),
                                             16, 0, 0);
        }
        __syncthreads();
#pragma unroll
        for (int kk = 0; kk < 2; ++kk) {
            const int klocal2 = (kk * 32 + lk * 8) * 2;
            bf16x8 av[4], bv[4];
#pragma unroll
            for (int m = 0; m < 4; m++) {
                int row = wm * 64 + m * 16 + lr;
                av[m] = *(const bf16x8*)((const char*)Asm + row * 128 + (klocal2 ^ ((row & 7) << 4)));
            }
#pragma unroll
            for (int n2 = 0; n2 < 4; n2++) {
                int row = wn * 64 + n2 * 16 + lr;
                bv[n2] = *(const bf16x8*)((const char*)Bsm + row * 128 + (klocal2 ^ ((row & 7) << 4)));
            }
#pragma unroll
            for (int m = 0; m < 4; m++)
#pragma unroll
                for (int n2 = 0; n2 < 4; n2++)
                    acc[m][n2] = __builtin_amdgcn_mfma_f32_16x16x32_bf16(av[m], bv[n2], acc[m][n2], 0, 0, 0);
        }
        __syncthreads();
    }

    if (MODE == 0) {
        // ---- epilogue: 2 phases x 64 rows, bf16 [64][136] LDS, u16x8 coalesced stores ----
#pragma unroll
        for (int ph = 0; ph < 2; ++ph) {
            if (wm == ph) {
#pragma unroll
                for (int m = 0; m < 4; m++)
#pragma unroll
                    for (int n2 = 0; n2 < 4; n2++) {
                        int col = wn * 64 + n2 * 16 + lr;
#pragma unroll
                        for (int j = 0; j < 4; j++)
                            SMEM[(m * 16 + lk * 4 + j) * 136 + col] = f2bf(acc[m][n2][j]);
                    }
            }
            __syncthreads();
#pragma unroll
            for (int cc2 = 0; cc2 < 4; ++cc2) {
                int cidx = cc2 * 256 + t;                // 1024 chunks = 64 rows x 16
                int rl = cidx >> 4, colc = cidx & 15;
                int cgl = col0 + colc * 8;
                if (cgl < NTOT) {
                    u16x8 v = *(const u16x8*)&SMEM[rl * 136 + colc * 8];
                    int rgl = row0 + ph * 64 + rl;
                    int which = cgl / 576, rem = cgl - which * 576;
                    int hh = rem / 72, dd = rem - hh * 72;
                    u16* dst = which == 0 ? Qp : (which == 1 ? Kp : Vp);
                    int b = rgl / NN, n = rgl - b * NN;
                    *(u16x8*)(dst + ((size_t)(b * 8 + hh) * NN + n) * 72 + dd) = v;
                }
            }
            __syncthreads();
        }
    } else {
        // ---- epilogue: 4 phases x 32 rows, f32 [32][136] LDS, f32x4 coalesced stores ----
        float* Ef = (float*)SMEM;
#pragma unroll
        for (int ph = 0; ph < 4; ++ph) {
            if (wm == (ph >> 1)) {
#pragma unroll
                for (int mm = 0; mm < 2; mm++) {
                    int m = (ph & 1) * 2 + mm;
#pragma unroll
                    for (int n2 = 0; n2 < 4; n2++) {
                        int col = wn * 64 + n2 * 16 + lr;
                        float addv = (MODE == 1) ? bias[min(col0 + col, NB - 1)] : 0.f;
#pragma unroll
                        for (int j = 0; j < 4; j++)
                            Ef[(mm * 16 + lk * 4 + j) * 136 + col] = acc[m][n2][j] + addv;
                    }
                }
            }
            __syncthreads();
#pragma unroll
            for (int cc2 = 0; cc2 < 4; ++cc2) {
                int cidx = cc2 * 256 + t;                // 1024 chunks = 32 rows x 32
                int rl = cidx >> 5, colc = cidx & 31;
                int cgl = col0 + colc * 4;
                int rgl = row0 + ph * 32 + rl;
                if (cgl < NB && rgl < M) {
                    f32x4 v = *(const f32x4*)&Ef[rl * 136 + colc * 4];
                    *(f32x4*)(Cf + (size_t)rgl * 576 + cgl) = v;
                }
            }
            __syncthreads();
        }
    }
}

// ---------- pool x (8x8 windows) -> px[b*49+ag][576] bf16;  pool(x)@Wq == pool(x@Wq) ----------
__global__ __launch_bounds__(256) void k_poolx(const u16* __restrict__ xb, u16* __restrict__ px) {
    const int t = threadIdx.x;
    const int b = blockIdx.x / 7, p1 = blockIdx.x % 7;
    for (int task = t; task < 504; task += 256) {
        int p2 = task / 72, c8 = task - p2 * 72;
        const u16* base = xb + ((size_t)b * NN + (p1 * 8) * 56 + p2 * 8) * CC + c8 * 8;
        float s[8] = {0.f, 0.f, 0.f, 0.f, 0.f, 0.f, 0.f, 0.f};
        for (int y = 0; y < 8; ++y)
#pragma unroll
            for (int x = 0; x < 8; ++x) {
                u16x8 v = *(const u16x8*)(base + (size_t)(y * 56 + x) * CC);
#pragma unroll
                for (int j = 0; j < 8; j++) s[j] += bf2f(v[j]);
            }
        u16x8 o;
#pragma unroll
        for (int j = 0; j < 8; j++) o[j] = f2bf(s[j] * 0.015625f);
        *(u16x8*)(px + (size_t)(b * AGN + p1 * 7 + p2) * CC + c8 * 8) = o;
    }
}

// ---------- stage A (MFMA): S^T = mfma(K, a), online softmax per agent-col, PV = mfma(P, V^T) ----------
__global__ __launch_bounds__(256) void k_stageA(const u16* __restrict__ Kp, const u16* __restrict__ Vp,
                                                const float* __restrict__ a_f, const float* __restrict__ b1,
                                                float* __restrict__ part) {
    const int t = threadIdx.x, lane = t & 63, w = t >> 6;
    const int c = lane & 15, g = lane >> 4;
    const int bh = blockIdx.y, b = bh >> 3, h = bh & 7;
    const int chunk = blockIdx.x;                        // 0..6

    __shared__ u16 A_lds[64][104];
    __shared__ u16 K_lds[64][104];
    __shared__ u16 Vt[80][72];
    __shared__ u16 P_lds[64][72];

    for (int i = t; i < 64 * 104; i += 256) {
        int r = i / 104, cc = i - r * 104;
        if (cc >= 72 || r >= 49) A_lds[r][cc] = 0;
        if (cc >= 72) K_lds[r][cc] = 0;
    }
    for (int i = t; i < 8 * 72; i += 256) Vt[72 + i / 72][i % 72] = 0;
    for (int i = t; i < 49 * 72; i += 256) {
        int r = i / 72, d = i - r * 72;
        A_lds[r][d] = f2bf(a_f[(size_t)(b * 49 + r) * CC + h * 72 + d] * SCALE);
    }
    __syncthreads();

    bf16x8 bfA[3];
#pragma unroll
    for (int ks = 0; ks < 3; ++ks) bfA[ks] = *(const bf16x8*)&A_lds[16 * w + c][8 * g + 32 * ks];

    float m_run = -1e30f, l_run = 0.f;
    f32x4 acc[5];
#pragma unroll
    for (int dt = 0; dt < 5; ++dt) acc[dt] = (f32x4)0.f;

    const u16* kb = Kp + ((size_t)(b * 8 + h) * NN + chunk * 448) * 72;
    const u16* vb = Vp + ((size_t)(b * 8 + h) * NN + chunk * 448) * 72;
    const int arow = min(16 * w + c, 48);

    for (int tile = 0; tile < 7; ++tile) {
        for (int i = t; i < 576; i += 256) {
            int nl = i / 9, ch = i - nl * 9;
            u16x8 kd = *(const u16x8*)(kb + (size_t)tile * 4608 + i * 8);
            *(u16x8*)&K_lds[nl][ch * 8] = kd;
        }
        for (int i = t; i < 576; i += 256) {
            int ch = i >> 6, nl = i & 63;
            u16x8 vd = *(const u16x8*)(vb + (size_t)tile * 4608 + (nl * 9 + ch) * 8);
#pragma unroll
            for (int j = 0; j < 8; j++) Vt[ch * 8 + j][nl] = vd[j];
        }
        __syncthreads();

        f32x4 sT[4];
        const int nbase = chunk * 448 + tile * 64 + 4 * g;
#pragma unroll
        for (int nm = 0; nm < 4; ++nm) {
            f32x4 sv;
#pragma unroll
            for (int j = 0; j < 4; j++)
                sv[j] = b1[(size_t)(h * NN + nbase + 16 * nm + j) * AGN + arow];
#pragma unroll
            for (int ks = 0; ks < 3; ++ks) {
                bf16x8 af = *(const bf16x8*)&K_lds[16 * nm + c][8 * g + 32 * ks];
                sv = __builtin_amdgcn_mfma_f32_16x16x32_bf16(af, bfA[ks], sv, 0, 0, 0);
            }
            sT[nm] = sv;
        }

        float mt = sT[0][0];
#pragma unroll
        for (int nm = 0; nm < 4; ++nm)
#pragma unroll
            for (int j = 0; j < 4; j++) mt = fmaxf(mt, sT[nm][j]);
        mt = fmaxf(mt, __shfl_xor(mt, 16, 64));
        mt = fmaxf(mt, __shfl_xor(mt, 32, 64));
        float mnew = fmaxf(m_run, mt);
        float ps = 0.f;
#pragma unroll
        for (int nm = 0; nm < 4; ++nm) {
            float p0 = __expf(sT[nm][0] - mnew);
            float p1 = __expf(sT[nm][1] - mnew);
            float p2 = __expf(sT[nm][2] - mnew);
            float p3 = __expf(sT[nm][3] - mnew);
            ps += (p0 + p1) + (p2 + p3);
            unsigned pk01 = ((unsigned)f2bf(p1) << 16) | f2bf(p0);
            unsigned pk23 = ((unsigned)f2bf(p3) << 16) | f2bf(p2);
            unsigned* dst = (unsigned*)&P_lds[16 * w + c][16 * nm + 4 * g];
            dst[0] = pk01; dst[1] = pk23;
        }
        ps += __shfl_xor(ps, 16, 64);
        ps += __shfl_xor(ps, 32, 64);
        float rsc = __expf(m_run - mnew);
        l_run = l_run * rsc + ps;
        m_run = mnew;

        float rj[4];
#pragma unroll
        for (int j = 0; j < 4; j++) rj[j] = __shfl(rsc, 4 * g + j, 64);
        bf16x8 pa[2];
#pragma unroll
        for (int ks = 0; ks < 2; ++ks) pa[ks] = *(const bf16x8*)&P_lds[16 * w + c][8 * g + 32 * ks];
#pragma unroll
        for (int dt = 0; dt < 5; ++dt) {
            f32x4 a0 = acc[dt];
#pragma unroll
            for (int j = 0; j < 4; j++) a0[j] *= rj[j];
#pragma unroll
            for (int ks = 0; ks < 2; ++ks) {
                bf16x8 vf = *(const bf16x8*)&Vt[16 * dt + c][8 * g + 32 * ks];
                a0 = __builtin_amdgcn_mfma_f32_16x16x32_bf16(pa[ks], vf, a0, 0, 0, 0);
            }
            acc[dt] = a0;
        }
        __syncthreads();
    }

    const size_t pbase = (size_t)(bh * NCH + chunk) * (49 * 74);
#pragma unroll
    for (int dt = 0; dt < 5; ++dt) {
        int d = 16 * dt + c;
        if (d < 72) {
#pragma unroll
            for (int j = 0; j < 4; j++) {
                int agent = 16 * w + 4 * g + j;
                if (agent < 49) part[pbase + agent * 74 + d] = acc[dt][j];
            }
        }
    }
    if (g == 0) {
        int agent = 16 * w + c;
        if (agent < 49) {
            part[pbase + agent * 74 + 72] = m_run;
            part[pbase + agent * 74 + 73] = l_run;
        }
    }
}

// ---------- reduce partials across NCH chunks ----------
__global__ __launch_bounds__(256) void k_reduceA(const float* __restrict__ part, float* __restrict__ agv) {
    const int bh = blockIdx.x, t = threadIdx.x;
    const float* pb = part + (size_t)bh * NCH * (49 * 74);
    for (int idx = t; idx < 49 * 72; idx += 256) {
        int row = idx / 72, d = idx - row * 72;
        float m = -1e30f;
#pragma unroll
        for (int c = 0; c < NCH; c++) m = fmaxf(m, pb[c * (49 * 74) + row * 74 + 72]);
        float accv = 0.f, l = 0.f;
#pragma unroll
        for (int c = 0; c < NCH; c++) {
            const float* pc = pb + c * (49 * 74) + row * 74;
            float e = __expf(pc[72] - m);
            accv += pc[d] * e;
            l += pc[73] * e;
        }
        agv[(size_t)(bh * 49 + row) * 72 + d] = accv / l;
    }
}

// ---------- stage B (MFMA): S = mfma(agents, q) -> softmax over 49 -> PV = mfma(P^T, av^T) ----------
__global__ __launch_bounds__(256) void k_stageB(const u16* __restrict__ Qp, const float* __restrict__ a_f,
                                                const float* __restrict__ agv, const float* __restrict__ b2p,
                                                u16* __restrict__ oat) {
    const int t = threadIdx.x, lane = t & 63, w = t >> 6;
    const int c = lane & 15, g = lane >> 4;
    const int bh = blockIdx.y, b = bh >> 3, h = bh & 7;
    const int n0 = blockIdx.x * 256;

    __shared__ u16 A_lds[64][104];
    __shared__ u16 avT[80][72];
    __shared__ u16 Pt[4][64][76];

    for (int i = t; i < 64 * 104; i += 256) {
        int r = i / 104, cc = i - r * 104;
        if (cc >= 72 || r >= 49) A_lds[r][cc] = 0;
    }
    for (int i = t; i < 80 * 72; i += 256) ((u16*)avT)[i] = 0;
    __syncthreads();
    for (int i = t; i < 49 * 72; i += 256) {
        int r = i / 72, d = i - r * 72;
        A_lds[r][d] = f2bf(a_f[(size_t)(b * 49 + r) * CC + h * 72 + d] * SCALE);
        avT[d][r]   = f2bf(agv[(size_t)(bh * 49 + r) * 72 + d]);
    }
    __syncthreads();

    bf16x8 afr[4][3];
#pragma unroll
    for (int mt = 0; mt < 4; ++mt)
#pragma unroll
        for (int ks = 0; ks < 3; ++ks) afr[mt][ks] = *(const bf16x8*)&A_lds[16 * mt + c][8 * g + 32 * ks];

    const int nw0 = n0 + w * 64;
#pragma unroll
    for (int cg = 0; cg < 4; ++cg) {
        const int n = nw0 + 16 * cg + c;
        const int ne = min(n, NN - 1);
        const u16* qp = Qp + ((size_t)(b * 8 + h) * NN + ne) * 72;
        bf16x8 qf[3];
#pragma unroll
        for (int ks = 0; ks < 3; ++ks) qf[ks] = *(const bf16x8*)(qp + 8 * g + 32 * ks);
        const float* bp = b2p + (size_t)(h * NN + ne) * 64;
        f32x4 sv[4];
#pragma unroll
        for (int mt = 0; mt < 4; ++mt) sv[mt] = *(const f32x4*)(bp + 16 * mt + 4 * g);
#pragma unroll
        for (int ks = 0; ks < 3; ++ks)
#pragma unroll
            for (int mt = 0; mt < 4; ++mt)
                sv[mt] = __builtin_amdgcn_mfma_f32_16x16x32_bf16(afr[mt][ks], qf[ks], sv[mt], 0, 0, 0);
        float mx = sv[0][0];
#pragma unroll
        for (int mt = 0; mt < 4; ++mt)
#pragma unroll
            for (int j = 0; j < 4; j++) mx = fmaxf(mx, sv[mt][j]);
        mx = fmaxf(mx, __shfl_xor(mx, 16, 64));
        mx = fmaxf(mx, __shfl_xor(mx, 32, 64));
        float ps = 0.f;
#pragma unroll
        for (int mt = 0; mt < 4; ++mt) {
#pragma unroll
            for (int j = 0; j < 4; j++) { sv[mt][j] = __expf(sv[mt][j] - mx); ps += sv[mt][j]; }
        }
        ps += __shfl_xor(ps, 16, 64);
        ps += __shfl_xor(ps, 32, 64);
        float inv = 1.f / ps;
#pragma unroll
        for (int mt = 0; mt < 4; ++mt) {
            unsigned pk01 = ((unsigned)f2bf(sv[mt][1] * inv) << 16) | f2bf(sv[mt][0] * inv);
            unsigned pk23 = ((unsigned)f2bf(sv[mt][3] * inv) << 16) | f2bf(sv[mt][2] * inv);
            unsigned* dst = (unsigned*)&Pt[w][16 * cg + c][16 * mt + 4 * g];
            dst[0] = pk01; dst[1] = pk23;
        }
    }
    bf16x8 vfr[5][2];
#pragma unroll
    for (int dt = 0; dt < 5; ++dt)
#pragma unroll
        for (int ks = 0; ks < 2; ++ks) vfr[dt][ks] = *(const bf16x8*)&avT[16 * dt + c][8 * g + 32 * ks];
#pragma unroll
    for (int rt = 0; rt < 4; ++rt) {
        bf16x8 pf[2];
#pragma unroll
        for (int ks = 0; ks < 2; ++ks) pf[ks] = *(const bf16x8*)&Pt[w][16 * rt + c][8 * g + 32 * ks];
#pragma unroll
        for (int dt = 0; dt < 5; ++dt) {
            f32x4 a0 = (f32x4)0.f;
            a0 = __builtin_amdgcn_mfma_f32_16x16x32_bf16(pf[0], vfr[dt][0], a0, 0, 0, 0);
            a0 = __builtin_amdgcn_mfma_f32_16x16x32_bf16(pf[1], vfr[dt][1], a0, 0, 0, 0);
            int dd = 16 * dt + c;
            if (dd < 72) {
#pragma unroll
                for (int j = 0; j < 4; j++) {
                    int nn2 = nw0 + 16 * rt + 4 * g + j;
                    if (nn2 < NN) oat[((size_t)b * NN + nn2) * CC + h * 72 + dd] = f2bf(a0[j]);
                }
            }
        }
    }
}

// ---------- depthwise 3x3 conv + affine + relu + add (reg-resident weights) ----------
__global__ __launch_bounds__(576) void k_conv(const u16* __restrict__ Vp, const u16* __restrict__ oat,
                                              const float* __restrict__ w, const float* __restrict__ gamma,
                                              const float* __restrict__ beta, u16* __restrict__ pre) {
    const int t = threadIdx.x;
    const int g8 = t % 72;
    const int p  = t / 72;
    const int c0 = g8 * 8;
    const int hh = c0 / 72, dl = c0 - hh * 72;

    __shared__ float wlds[CC * 9];
    __shared__ float glds[CC], blds[CC];
    for (int i = t; i < CC * 9; i += 576) wlds[i] = w[i];
    glds[t < CC ? t : 0] = gamma[t < CC ? t : 0];
    blds[t < CC ? t : 0] = beta[t < CC ? t : 0];
    __syncthreads();

    float wv[8][9], gm[8], bt[8];
#pragma unroll
    for (int j = 0; j < 8; j++) {
#pragma unroll
        for (int tap = 0; tap < 9; tap++) wv[j][tap] = wlds[(c0 + j) * 9 + tap];
        gm[j] = glds[c0 + j]; bt[j] = blds[c0 + j];
    }

    for (int pt = blockIdx.x * 8 + p; pt < BB * NN; pt += gridDim.x * 8) {
        int b = pt / NN, n = pt - b * NN;
        int y = n / 56, x = n % 56;
        const u16* vbase = Vp + ((size_t)(b * 8 + hh) * NN) * 72 + dl;
        float a[8] = {0.f, 0.f, 0.f, 0.f, 0.f, 0.f, 0.f, 0.f};
#pragma unroll
        for (int dy = -1; dy <= 1; ++dy) {
            int yy = y + dy; if (yy < 0 || yy > 55) continue;
#pragma unroll
            for (int dx = -1; dx <= 1; ++dx) {
                int xx = x + dx; if (xx < 0 || xx > 55) continue;
                u16x8 vv = *(const u16x8*)(vbase + (size_t)(yy * 56 + xx) * 72);
                int tap = (dy + 1) * 3 + (dx + 1);
#pragma unroll
                for (int j = 0; j < 8; j++) a[j] += bf2f(vv[j]) * wv[j][tap];
            }
        }
        u16x8 ov = *(const u16x8*)(oat + (size_t)pt * CC + c0);
        u16x8 rr;
#pragma unroll
        for (int j = 0; j < 8; j++)
            rr[j] = f2bf(bf2f(ov[j]) + fmaxf(a[j] * gm[j] + bt[j], 0.f));
        *(u16x8*)(pre + (size_t)pt * CC + c0) = rr;
    }
}

// ---------- launch ----------
extern "C" void kernel_launch(void* const* d_in, const int* in_sizes, int n_in,
                              void* d_out, int out_size, void* d_ws, size_t ws_size,
                              hipStream_t stream) {
    const float* x     = (const float*)d_in[0];
    const float* Wq    = (const float*)d_in[1];
    const float* Wkv   = (const float*)d_in[2];
    const float* an_b  = (const float*)d_in[3];
    const float* na_b  = (const float*)d_in[4];
    const float* ah_b  = (const float*)d_in[5];
    const float* aw_b  = (const float*)d_in[6];
    const float* ha_b  = (const float*)d_in[7];
    const float* wa_b  = (const float*)d_in[8];
    const float* dwcw  = (const float*)d_in[9];
    const float* gam   = (const float*)d_in[10];
    const float* bet   = (const float*)d_in[11];
    const float* projw = (const float*)d_in[12];
    const float* projb = (const float*)d_in[13];
    float* out = (float*)d_out;

    char* ws = (char*)d_ws;
    u16* wbT  = (u16*)(ws + 0);                          //  1,990,656
    u16* wpT  = (u16*)(ws + 1990656);                    //    663,552
    u16* xb   = (u16*)(ws + 2654208);                    // 57,802,752 (reused: stageA partials, then 'pre')
    u16* Qp   = (u16*)(ws + 60456960);                   // 57,802,752
    u16* Kp   = (u16*)(ws + 118259712);                  // 57,802,752 (reused as bf16 outatt after stageA)
    u16* Vp   = (u16*)(ws + 176062464);                  // 57,802,752
    float* af = (float*)(ws + 233865216);                //  1,806,336
    u16* px   = (u16*)(ws + 235671552);                  //    903,168 (agv region: disjoint lifetime)
    float* agv= (float*)(ws + 235671552);                //  1,806,336
    float* b1 = (float*)(ws + 237477888);                //  4,917,248  [h][n][49]
    float* b2p= (float*)(ws + 242395136);                //  6,422,528  [h][n][64] padded
    float* part = (float*)xb;                            // 12,995,584 (inside xb region)
    u16* obuf = Kp;

    k_cast_x<<<28224, 256, 0, stream>>>(x, xb);
    k_prep_w<<<5184, 256, 0, stream>>>(Wq, Wkv, projw, wbT, wpT);
    k_bias1<<<4802, 256, 0, stream>>>(an_b, ah_b, aw_b, b1);
    k_bias2<<<6272, 256, 0, stream>>>(na_b, ha_b, wa_b, b2p);
    k_poolx<<<112, 256, 0, stream>>>(xb, px);
    k_gemm<2><<<dim3(5, 7), 256, 0, stream>>>(px, wbT, nullptr, nullptr, nullptr, af, nullptr, 784);
    k_gemm<0><<<dim3(14, 392), 256, 0, stream>>>(xb, wbT, Qp, Kp, Vp, nullptr, nullptr, BB * NN);
    k_stageA<<<dim3(NCH, 128), 256, 0, stream>>>(Kp, Vp, af, b1, part);
    k_reduceA<<<128, 256, 0, stream>>>(part, agv);
    k_stageB<<<dim3(13, 128), 256, 0, stream>>>(Qp, af, agv, b2p, obuf);
    k_conv<<<784, 576, 0, stream>>>(Vp, obuf, dwcw, gam, bet, xb /*pre*/);
    k_gemm<1><<<dim3(5, 392), 256, 0, stream>>>(xb /*pre*/, wpT, nullptr, nullptr, nullptr, out, projb, BB * NN);
}

// Round 8
// 487.747 us; speedup vs baseline: 2.9160x; 1.1318x over previous
//
#include <hip/hip_runtime.h>
#include <stdint.h>

// ---------- types ----------
typedef unsigned short u16;
typedef u16   u16x4 __attribute__((ext_vector_type(4)));
typedef u16   u16x8 __attribute__((ext_vector_type(8)));
typedef float f32x4 __attribute__((ext_vector_type(4)));
typedef __bf16 bf16x8 __attribute__((ext_vector_type(8)));

// ---------- constants ----------
#define BB    16
#define NN    3136
#define CC    576
#define HEADS 8
#define HD    72
#define AGN   49
#define NTOT  1728
#define NCH   6                      // stageA chunks: tiles {9,8,8,8,8,8} of 64 tokens -> 768 blocks = 3/CU
#define SCALE 0.1178511301977579f   // 72^-0.5

__device__ __forceinline__ u16 f2bf(float f) {
    unsigned u = __float_as_uint(f);
    return (u16)((u + 0x7fffu + ((u >> 16) & 1u)) >> 16);
}
__device__ __forceinline__ float bf2f(u16 u) {
    return __uint_as_float(((unsigned)u) << 16);
}

// ---------- cast x -> bf16 ----------
__global__ __launch_bounds__(256) void k_cast_x(const float* __restrict__ x, u16* __restrict__ xb) {
    size_t i = (size_t)blockIdx.x * 256 + threadIdx.x;
    f32x4 v = *(const f32x4*)(x + i * 4);
    u16x4 o; o[0] = f2bf(v[0]); o[1] = f2bf(v[1]); o[2] = f2bf(v[2]); o[3] = f2bf(v[3]);
    *(u16x4*)(xb + i * 4) = o;
}

// ---------- pack transposed bf16 weights ----------
__global__ __launch_bounds__(256) void k_prep_w(const float* __restrict__ Wq, const float* __restrict__ Wkv,
                                                const float* __restrict__ Wp,
                                                u16* __restrict__ wbT, u16* __restrict__ wpT) {
    int idx = blockIdx.x * 256 + threadIdx.x;
    if (idx < NTOT * CC) {
        int nn = idx / CC, kk = idx % CC;
        float v = (nn < CC) ? Wq[kk * CC + nn] : Wkv[kk * (2 * CC) + (nn - CC)];
        wbT[idx] = f2bf(v);
    } else {
        int j = idx - NTOT * CC;
        int nn = j / CC, kk = j % CC;
        wpT[j] = f2bf(Wp[kk * CC + nn]);
    }
}

// ---------- jax.image.resize 'linear' 7x7 -> 56x56 ----------
__device__ __forceinline__ float bilerp7(const float* __restrict__ g, int oy, int ox) {
    float cy = (oy - 3.5f) * 0.125f;
    float cx = (ox - 3.5f) * 0.125f;
    float fy0 = floorf(cy), fx0 = floorf(cx);
    float ty = cy - fy0, tx = cx - fx0;
    int iy0 = (int)fy0, ix0 = (int)fx0;
    int y0 = min(6, max(0, iy0)), y1 = min(6, max(0, iy0 + 1));
    int x0 = min(6, max(0, ix0)), x1 = min(6, max(0, ix0 + 1));
    float g00 = g[y0 * 7 + x0], g01 = g[y0 * 7 + x1];
    float g10 = g[y1 * 7 + x0], g11 = g[y1 * 7 + x1];
    return (1.f - ty) * ((1.f - tx) * g00 + tx * g01) + ty * ((1.f - tx) * g10 + tx * g11);
}

// bias1 layout: [h][n][49]
__global__ __launch_bounds__(256) void k_bias1(const float* __restrict__ an, const float* __restrict__ ah,
                                               const float* __restrict__ aw, float* __restrict__ b1) {
    int idx = blockIdx.x * 256 + threadIdx.x;
    int ag = idx % AGN; int r = idx / AGN; int n = r % NN; int h = r / NN;
    int y = n / 56, x = n % 56;
    float v = bilerp7(an + (h * AGN + ag) * 49, y, x);
    b1[idx] = v + ah[(h * AGN + ag) * 56 + y] + aw[(h * AGN + ag) * 56 + x];
}

// bias2 layout: [h][n][64] f32, pad ag>=49 with -1e30 (softmax kills them)
__global__ __launch_bounds__(256) void k_bias2(const float* __restrict__ na, const float* __restrict__ ha,
                                               const float* __restrict__ wa, float* __restrict__ b2p) {
    int idx = blockIdx.x * 256 + threadIdx.x;
    int ag = idx & 63; int r = idx >> 6; int n = r % NN; int h = r / NN;
    float v;
    if (ag < AGN) {
        int y = n / 56, x = n % 56;
        v = bilerp7(na + (h * AGN + ag) * 49, y, x)
          + ha[(h * 56 + y) * AGN + ag] + wa[(h * 56 + x) * AGN + ag];
    } else v = -1e30f;
    b2p[idx] = v;
}

// ---------- MFMA GEMM: A[M x 576] @ Bt[NB x 576]^T,  BM=128 BN=128 BK=64, XCD-swizzled ----------
// MODE 0: bf16 scatter to Qp/Kp/Vp (NB=1728) [R6 epilogue: scatter is absorbed by L2 write-combining;
//         LDS-coalesced variant measured SLOWER (R7: +15us, VGPR 84->116)]
// MODE 1: f32+bias to Cf (NB=576); MODE 2: f32 to Cf  -- via LDS-coalesced f32 epilogue
template<int MODE>
__global__ __launch_bounds__(256) void k_gemm(const u16* __restrict__ A, const u16* __restrict__ Bt,
                                              u16* __restrict__ Qp, u16* __restrict__ Kp, u16* __restrict__ Vp,
                                              float* __restrict__ Cf, const float* __restrict__ bias,
                                              const int M) {
    const int NB = (MODE == 0) ? NTOT : CC;
    __shared__ u16 SMEM[2 * 128 * 64];                   // 32 KB: Asm | Bsm, reused by f32 epilogue
    u16* Asm = SMEM;
    u16* Bsm = SMEM + 128 * 64;
    const int t = threadIdx.x, lane = t & 63, wid = t >> 6;
    const int wm = wid & 1, wn = wid >> 1;
    // bijective XCD swizzle (m204)
    const int nwg = gridDim.x * gridDim.y;
    const int id = blockIdx.y * gridDim.x + blockIdx.x;
    const int qq = nwg >> 3, rr = nwg & 7;
    const int xcd = id & 7, off = id >> 3;
    const int nid = (xcd < rr ? xcd * (qq + 1) : rr * (qq + 1) + (xcd - rr) * qq) + off;
    const int row0 = (nid / gridDim.x) * 128, col0 = (nid % gridDim.x) * 128;
    const int lr = lane & 15, lk = lane >> 4;
    f32x4 acc[4][4];
#pragma unroll
    for (int m = 0; m < 4; m++)
#pragma unroll
        for (int n2 = 0; n2 < 4; n2++) acc[m][n2] = (f32x4)0.f;

    for (int kt = 0; kt < 9; ++kt) {
        const int k0 = kt * 64;
#pragma unroll
        for (int it = 0; it < 4; ++it) {
            int flat = it * 256 + wid * 64 + lane;
            int r = flat >> 3, lc = (flat & 7) ^ (r & 7);
            int arow = min(row0 + r, M - 1);
            const u16* src = A + (size_t)arow * CC + k0 + lc * 8;
            __builtin_amdgcn_global_load_lds((const __attribute__((address_space(1))) void*)src,
                                             (__attribute__((address_space(3))) void*)(&Asm[(it * 256 + wid * 64) * 8]),
                                             16, 0, 0);
        }
#pragma unroll
        for (int it = 0; it < 4; ++it) {
            int flat = it * 256 + wid * 64 + lane;
            int r = flat >> 3, lc = (flat & 7) ^ (r & 7);
            int brow = min(col0 + r, NB - 1);
            const u16* src = Bt + (size_t)brow * CC + k0 + lc * 8;
            __builtin_amdgcn_global_load_lds((const __attribute__((address_space(1))) void*)src,
                                             (__attribute__((address_space(3))) void*)(&Bsm[(it * 256 + wid * 64) * 8]),
                                             16, 0, 0);
        }
        __syncthreads();
#pragma unroll
        for (int kk = 0; kk < 2; ++kk) {
            const int klocal2 = (kk * 32 + lk * 8) * 2;
            bf16x8 av[4], bv[4];
#pragma unroll
            for (int m = 0; m < 4; m++) {
                int row = wm * 64 + m * 16 + lr;
                av[m] = *(const bf16x8*)((const char*)Asm + row * 128 + (klocal2 ^ ((row & 7) << 4)));
            }
#pragma unroll
            for (int n2 = 0; n2 < 4; n2++) {
                int row = wn * 64 + n2 * 16 + lr;
                bv[n2] = *(const bf16x8*)((const char*)Bsm + row * 128 + (klocal2 ^ ((row & 7) << 4)));
            }
#pragma unroll
            for (int m = 0; m < 4; m++)
#pragma unroll
                for (int n2 = 0; n2 < 4; n2++)
                    acc[m][n2] = __builtin_amdgcn_mfma_f32_16x16x32_bf16(av[m], bv[n2], acc[m][n2], 0, 0, 0);
        }
        __syncthreads();
    }

    if (MODE == 0) {
        // direct scatter epilogue (R6)
#pragma unroll
        for (int n2 = 0; n2 < 4; n2++) {
            int cgl = col0 + wn * 64 + n2 * 16 + lr;
            if (cgl >= NB) continue;
            int which = cgl / 576;
            int rem = cgl - which * 576;
            int hh = rem / 72;
            int dd = rem - hh * 72;
            u16* dst = which == 0 ? Qp : (which == 1 ? Kp : Vp);
#pragma unroll
            for (int m = 0; m < 4; m++)
#pragma unroll
                for (int j = 0; j < 4; j++) {
                    int rgl = row0 + wm * 64 + m * 16 + lk * 4 + j;
                    int b = rgl / NN, n = rgl - b * NN;
                    dst[((size_t)(b * 8 + hh) * NN + n) * 72 + dd] = f2bf(acc[m][n2][j]);
                }
        }
    } else {
        // LDS-coalesced f32 epilogue: 4 phases x 32 rows
        float* Ef = (float*)SMEM;
#pragma unroll
        for (int ph = 0; ph < 4; ++ph) {
            if (wm == (ph >> 1)) {
#pragma unroll
                for (int mm = 0; mm < 2; mm++) {
                    int m = (ph & 1) * 2 + mm;
#pragma unroll
                    for (int n2 = 0; n2 < 4; n2++) {
                        int col = wn * 64 + n2 * 16 + lr;
                        float addv = (MODE == 1) ? bias[min(col0 + col, NB - 1)] : 0.f;
#pragma unroll
                        for (int j = 0; j < 4; j++)
                            Ef[(mm * 16 + lk * 4 + j) * 136 + col] = acc[m][n2][j] + addv;
                    }
                }
            }
            __syncthreads();
#pragma unroll
            for (int cc2 = 0; cc2 < 4; ++cc2) {
                int cidx = cc2 * 256 + t;
                int rl = cidx >> 5, colc = cidx & 31;
                int cgl = col0 + colc * 4;
                int rgl = row0 + ph * 32 + rl;
                if (cgl < NB && rgl < M) {
                    f32x4 v = *(const f32x4*)&Ef[rl * 136 + colc * 4];
                    *(f32x4*)(Cf + (size_t)rgl * 576 + cgl) = v;
                }
            }
            __syncthreads();
        }
    }
}

// ---------- pool x (8x8 windows) -> px[b*49+ag][576] bf16;  pool(x)@Wq == pool(x@Wq) ----------
__global__ __launch_bounds__(256) void k_poolx(const u16* __restrict__ xb, u16* __restrict__ px) {
    const int t = threadIdx.x;
    const int b = blockIdx.x / 7, p1 = blockIdx.x % 7;
    for (int task = t; task < 504; task += 256) {
        int p2 = task / 72, c8 = task - p2 * 72;
        const u16* base = xb + ((size_t)b * NN + (p1 * 8) * 56 + p2 * 8) * CC + c8 * 8;
        float s[8] = {0.f, 0.f, 0.f, 0.f, 0.f, 0.f, 0.f, 0.f};
        for (int y = 0; y < 8; ++y)
#pragma unroll
            for (int x = 0; x < 8; ++x) {
                u16x8 v = *(const u16x8*)(base + (size_t)(y * 56 + x) * CC);
#pragma unroll
                for (int j = 0; j < 8; j++) s[j] += bf2f(v[j]);
            }
        u16x8 o;
#pragma unroll
        for (int j = 0; j < 8; j++) o[j] = f2bf(s[j] * 0.015625f);
        *(u16x8*)(px + (size_t)(b * AGN + p1 * 7 + p2) * CC + c8 * 8) = o;
    }
}

// ---------- stage A (MFMA): S^T = mfma(K, a), online softmax per agent-col, PV = mfma(P, V^T) ----------
__global__ __launch_bounds__(256) void k_stageA(const u16* __restrict__ Kp, const u16* __restrict__ Vp,
                                                const float* __restrict__ a_f, const float* __restrict__ b1,
                                                float* __restrict__ part) {
    const int t = threadIdx.x, lane = t & 63, w = t >> 6;
    const int c = lane & 15, g = lane >> 4;
    const int bh = blockIdx.y, b = bh >> 3, h = bh & 7;
    const int chunk = blockIdx.x;                        // 0..5
    const int t0 = (chunk == 0) ? 0 : 9 + 8 * (chunk - 1);
    const int ntile = (chunk == 0) ? 9 : 8;

    __shared__ u16 A_lds[64][104];
    __shared__ u16 K_lds[64][104];
    __shared__ u16 Vt[80][72];
    __shared__ u16 P_lds[64][72];

    for (int i = t; i < 64 * 104; i += 256) {
        int r = i / 104, cc = i - r * 104;
        if (cc >= 72 || r >= 49) A_lds[r][cc] = 0;
        if (cc >= 72) K_lds[r][cc] = 0;
    }
    for (int i = t; i < 8 * 72; i += 256) Vt[72 + i / 72][i % 72] = 0;
    for (int i = t; i < 49 * 72; i += 256) {
        int r = i / 72, d = i - r * 72;
        A_lds[r][d] = f2bf(a_f[(size_t)(b * 49 + r) * CC + h * 72 + d] * SCALE);
    }
    __syncthreads();

    bf16x8 bfA[3];
#pragma unroll
    for (int ks = 0; ks < 3; ++ks) bfA[ks] = *(const bf16x8*)&A_lds[16 * w + c][8 * g + 32 * ks];

    float m_run = -1e30f, l_run = 0.f;
    f32x4 acc[5];
#pragma unroll
    for (int dt = 0; dt < 5; ++dt) acc[dt] = (f32x4)0.f;

    const u16* kb = Kp + ((size_t)(b * 8 + h) * NN + t0 * 64) * 72;
    const u16* vb = Vp + ((size_t)(b * 8 + h) * NN + t0 * 64) * 72;
    const int arow = min(16 * w + c, 48);

    for (int tile = 0; tile < ntile; ++tile) {
        for (int i = t; i < 576; i += 256) {
            int nl = i / 9, ch = i - nl * 9;
            u16x8 kd = *(const u16x8*)(kb + (size_t)tile * 4608 + i * 8);
            *(u16x8*)&K_lds[nl][ch * 8] = kd;
        }
        for (int i = t; i < 576; i += 256) {
            int ch = i >> 6, nl = i & 63;
            u16x8 vd = *(const u16x8*)(vb + (size_t)tile * 4608 + (nl * 9 + ch) * 8);
#pragma unroll
            for (int j = 0; j < 8; j++) Vt[ch * 8 + j][nl] = vd[j];
        }
        __syncthreads();

        f32x4 sT[4];
        const int nbase = (t0 + tile) * 64 + 4 * g;
#pragma unroll
        for (int nm = 0; nm < 4; ++nm) {
            f32x4 sv;
#pragma unroll
            for (int j = 0; j < 4; j++)
                sv[j] = b1[(size_t)(h * NN + nbase + 16 * nm + j) * AGN + arow];
#pragma unroll
            for (int ks = 0; ks < 3; ++ks) {
                bf16x8 af = *(const bf16x8*)&K_lds[16 * nm + c][8 * g + 32 * ks];
                sv = __builtin_amdgcn_mfma_f32_16x16x32_bf16(af, bfA[ks], sv, 0, 0, 0);
            }
            sT[nm] = sv;
        }

        float mt = sT[0][0];
#pragma unroll
        for (int nm = 0; nm < 4; ++nm)
#pragma unroll
            for (int j = 0; j < 4; j++) mt = fmaxf(mt, sT[nm][j]);
        mt = fmaxf(mt, __shfl_xor(mt, 16, 64));
        mt = fmaxf(mt, __shfl_xor(mt, 32, 64));
        float mnew = fmaxf(m_run, mt);
        float ps = 0.f;
#pragma unroll
        for (int nm = 0; nm < 4; ++nm) {
            float p0 = __expf(sT[nm][0] - mnew);
            float p1 = __expf(sT[nm][1] - mnew);
            float p2 = __expf(sT[nm][2] - mnew);
            float p3 = __expf(sT[nm][3] - mnew);
            ps += (p0 + p1) + (p2 + p3);
            unsigned pk01 = ((unsigned)f2bf(p1) << 16) | f2bf(p0);
            unsigned pk23 = ((unsigned)f2bf(p3) << 16) | f2bf(p2);
            unsigned* dst = (unsigned*)&P_lds[16 * w + c][16 * nm + 4 * g];
            dst[0] = pk01; dst[1] = pk23;
        }
        ps += __shfl_xor(ps, 16, 64);
        ps += __shfl_xor(ps, 32, 64);
        float rsc = __expf(m_run - mnew);
        l_run = l_run * rsc + ps;
        m_run = mnew;

        float rj[4];
#pragma unroll
        for (int j = 0; j < 4; j++) rj[j] = __shfl(rsc, 4 * g + j, 64);
        bf16x8 pa[2];
#pragma unroll
        for (int ks = 0; ks < 2; ++ks) pa[ks] = *(const bf16x8*)&P_lds[16 * w + c][8 * g + 32 * ks];
#pragma unroll
        for (int dt = 0; dt < 5; ++dt) {
            f32x4 a0 = acc[dt];
#pragma unroll
            for (int j = 0; j < 4; j++) a0[j] *= rj[j];
#pragma unroll
            for (int ks = 0; ks < 2; ++ks) {
                bf16x8 vf = *(const bf16x8*)&Vt[16 * dt + c][8 * g + 32 * ks];
                a0 = __builtin_amdgcn_mfma_f32_16x16x32_bf16(pa[ks], vf, a0, 0, 0, 0);
            }
            acc[dt] = a0;
        }
        __syncthreads();
    }

    const size_t pbase = (size_t)(bh * NCH + chunk) * (49 * 74);
#pragma unroll
    for (int dt = 0; dt < 5; ++dt) {
        int d = 16 * dt + c;
        if (d < 72) {
#pragma unroll
            for (int j = 0; j < 4; j++) {
                int agent = 16 * w + 4 * g + j;
                if (agent < 49) part[pbase + agent * 74 + d] = acc[dt][j];
            }
        }
    }
    if (g == 0) {
        int agent = 16 * w + c;
        if (agent < 49) {
            part[pbase + agent * 74 + 72] = m_run;
            part[pbase + agent * 74 + 73] = l_run;
        }
    }
}

// ---------- reduce partials across NCH chunks ----------
__global__ __launch_bounds__(256) void k_reduceA(const float* __restrict__ part, float* __restrict__ agv) {
    const int bh = blockIdx.x, t = threadIdx.x;
    const float* pb = part + (size_t)bh * NCH * (49 * 74);
    for (int idx = t; idx < 49 * 72; idx += 256) {
        int row = idx / 72, d = idx - row * 72;
        float m = -1e30f;
#pragma unroll
        for (int c = 0; c < NCH; c++) m = fmaxf(m, pb[c * (49 * 74) + row * 74 + 72]);
        float accv = 0.f, l = 0.f;
#pragma unroll
        for (int c = 0; c < NCH; c++) {
            const float* pc = pb + c * (49 * 74) + row * 74;
            float e = __expf(pc[72] - m);
            accv += pc[d] * e;
            l += pc[73] * e;
        }
        agv[(size_t)(bh * 49 + row) * 72 + d] = accv / l;
    }
}

// ---------- stage B + conv fused: QK softmax PV (oat -> LDS), then dwconv+relu+add -> pre ----------
__global__ __launch_bounds__(256) void k_stageBC(const u16* __restrict__ Qp, const float* __restrict__ a_f,
                                                 const float* __restrict__ agv, const float* __restrict__ b2p,
                                                 const u16* __restrict__ Vp, const float* __restrict__ cw,
                                                 const float* __restrict__ gamma, const float* __restrict__ beta,
                                                 u16* __restrict__ pre) {
    const int t = threadIdx.x, lane = t & 63, w = t >> 6;
    const int c = lane & 15, g = lane >> 4;
    const int bh = blockIdx.y, b = bh >> 3, h = bh & 7;
    const int n0 = blockIdx.x * 256;

    __shared__ u16 A_lds[64][104];                       // 13312 B
    __shared__ u16 avT[80][72];                          // 11520 B
    __shared__ u16 Pt[4][64][80];                        // 40960 B: P then (reused in-band) bf16 oat
    __shared__ float wle[72 * 9];                        //  2592 B (this head's conv weights)
    __shared__ float gle[72], ble[72];                   //   576 B

    for (int i = t; i < 64 * 104; i += 256) {
        int r = i / 104, cc = i - r * 104;
        if (cc >= 72 || r >= 49) A_lds[r][cc] = 0;
    }
    for (int i = t; i < 80 * 72; i += 256) ((u16*)avT)[i] = 0;
    for (int i = t; i < 648; i += 256) wle[i] = cw[h * 648 + i];
    if (t < 72) { gle[t] = gamma[h * 72 + t]; ble[t] = beta[h * 72 + t]; }
    __syncthreads();
    for (int i = t; i < 49 * 72; i += 256) {
        int r = i / 72, d = i - r * 72;
        A_lds[r][d] = f2bf(a_f[(size_t)(b * 49 + r) * CC + h * 72 + d] * SCALE);
        avT[d][r]   = f2bf(agv[(size_t)(bh * 49 + r) * 72 + d]);
    }
    __syncthreads();

    // hoisted agent A-frags (rows ag = 16mt + c)
    bf16x8 afr[4][3];
#pragma unroll
    for (int mt = 0; mt < 4; ++mt)
#pragma unroll
        for (int ks = 0; ks < 3; ++ks) afr[mt][ks] = *(const bf16x8*)&A_lds[16 * mt + c][8 * g + 32 * ks];

    const int nw0 = n0 + w * 64;
    // ---- QK + softmax over 49 agents ----
#pragma unroll
    for (int cg = 0; cg < 4; ++cg) {
        const int n = nw0 + 16 * cg + c;
        const int ne = min(n, NN - 1);
        const u16* qp = Qp + ((size_t)(b * 8 + h) * NN + ne) * 72;
        bf16x8 qf[3];
#pragma unroll
        for (int ks = 0; ks < 3; ++ks) qf[ks] = *(const bf16x8*)(qp + 8 * g + 32 * ks);  // k>=72 garbage x A-zero = 0
        const float* bp = b2p + (size_t)(h * NN + ne) * 64;
        f32x4 sv[4];
#pragma unroll
        for (int mt = 0; mt < 4; ++mt) sv[mt] = *(const f32x4*)(bp + 16 * mt + 4 * g);
#pragma unroll
        for (int ks = 0; ks < 3; ++ks)
#pragma unroll
            for (int mt = 0; mt < 4; ++mt)
                sv[mt] = __builtin_amdgcn_mfma_f32_16x16x32_bf16(afr[mt][ks], qf[ks], sv[mt], 0, 0, 0);
        float mx = sv[0][0];
#pragma unroll
        for (int mt = 0; mt < 4; ++mt)
#pragma unroll
            for (int j = 0; j < 4; j++) mx = fmaxf(mx, sv[mt][j]);
        mx = fmaxf(mx, __shfl_xor(mx, 16, 64));
        mx = fmaxf(mx, __shfl_xor(mx, 32, 64));
        float ps = 0.f;
#pragma unroll
        for (int mt = 0; mt < 4; ++mt) {
#pragma unroll
            for (int j = 0; j < 4; j++) { sv[mt][j] = __expf(sv[mt][j] - mx); ps += sv[mt][j]; }
        }
        ps += __shfl_xor(ps, 16, 64);
        ps += __shfl_xor(ps, 32, 64);
        float inv = 1.f / ps;
#pragma unroll
        for (int mt = 0; mt < 4; ++mt) {
            unsigned pk01 = ((unsigned)f2bf(sv[mt][1] * inv) << 16) | f2bf(sv[mt][0] * inv);
            unsigned pk23 = ((unsigned)f2bf(sv[mt][3] * inv) << 16) | f2bf(sv[mt][2] * inv);
            unsigned* dst = (unsigned*)&Pt[w][16 * cg + c][16 * mt + 4 * g];
            dst[0] = pk01; dst[1] = pk23;
        }
    }
    // ---- PV; result (bf16 oat) written back into Pt band-by-band (pf reg-loaded first; wave lockstep) ----
    bf16x8 vfr[5][2];
#pragma unroll
    for (int dt = 0; dt < 5; ++dt)
#pragma unroll
        for (int ks = 0; ks < 2; ++ks) vfr[dt][ks] = *(const bf16x8*)&avT[16 * dt + c][8 * g + 32 * ks];
#pragma unroll
    for (int rt = 0; rt < 4; ++rt) {
        bf16x8 pf[2];
#pragma unroll
        for (int ks = 0; ks < 2; ++ks) pf[ks] = *(const bf16x8*)&Pt[w][16 * rt + c][8 * g + 32 * ks];
#pragma unroll
        for (int dt = 0; dt < 5; ++dt) {
            f32x4 a0 = (f32x4)0.f;
            a0 = __builtin_amdgcn_mfma_f32_16x16x32_bf16(pf[0], vfr[dt][0], a0, 0, 0, 0);
            a0 = __builtin_amdgcn_mfma_f32_16x16x32_bf16(pf[1], vfr[dt][1], a0, 0, 0, 0);
            int dd = 16 * dt + c;
            if (dd < 72) {
#pragma unroll
                for (int j = 0; j < 4; j++)
                    Pt[w][16 * rt + 4 * g + j][dd] = f2bf(a0[j]);
            }
        }
    }
    __syncthreads();

    // ---- conv phase: dwc3x3(V) affine relu + oat(LDS), write pre ----
    const u16* PtF = &Pt[0][0][0];
    const u16* vh = Vp + ((size_t)(b * 8 + h) * NN) * 72;
    for (int task = t; task < 256 * 9; task += 256) {
        int tl = task / 9, ch = task - tl * 9;
        int n = n0 + tl;
        if (n >= NN) continue;
        int y = n / 56, x = n % 56;
        float a[8] = {0.f, 0.f, 0.f, 0.f, 0.f, 0.f, 0.f, 0.f};
#pragma unroll
        for (int dy = -1; dy <= 1; ++dy) {
            int yy = y + dy; if (yy < 0 || yy > 55) continue;
#pragma unroll
            for (int dx = -1; dx <= 1; ++dx) {
                int xx = x + dx; if (xx < 0 || xx > 55) continue;
                u16x8 vv = *(const u16x8*)(vh + (size_t)(yy * 56 + xx) * 72 + ch * 8);
                int tap = (dy + 1) * 3 + (dx + 1);
#pragma unroll
                for (int j = 0; j < 8; j++) a[j] += bf2f(vv[j]) * wle[(ch * 8 + j) * 9 + tap];
            }
        }
        u16x8 ov = *(const u16x8*)&PtF[tl * 80 + ch * 8];
        u16x8 rr2;
#pragma unroll
        for (int j = 0; j < 8; j++)
            rr2[j] = f2bf(bf2f(ov[j]) + fmaxf(a[j] * gle[ch * 8 + j] + ble[ch * 8 + j], 0.f));
        *(u16x8*)(pre + ((size_t)b * NN + n) * CC + h * 72 + ch * 8) = rr2;
    }
}

// ---------- launch ----------
extern "C" void kernel_launch(void* const* d_in, const int* in_sizes, int n_in,
                              void* d_out, int out_size, void* d_ws, size_t ws_size,
                              hipStream_t stream) {
    const float* x     = (const float*)d_in[0];
    const float* Wq    = (const float*)d_in[1];
    const float* Wkv   = (const float*)d_in[2];
    const float* an_b  = (const float*)d_in[3];
    const float* na_b  = (const float*)d_in[4];
    const float* ah_b  = (const float*)d_in[5];
    const float* aw_b  = (const float*)d_in[6];
    const float* ha_b  = (const float*)d_in[7];
    const float* wa_b  = (const float*)d_in[8];
    const float* dwcw  = (const float*)d_in[9];
    const float* gam   = (const float*)d_in[10];
    const float* bet   = (const float*)d_in[11];
    const float* projw = (const float*)d_in[12];
    const float* projb = (const float*)d_in[13];
    float* out = (float*)d_out;

    char* ws = (char*)d_ws;
    u16* wbT  = (u16*)(ws + 0);                          //  1,990,656
    u16* wpT  = (u16*)(ws + 1990656);                    //    663,552
    u16* xb   = (u16*)(ws + 2654208);                    // 57,802,752 (reused: stageA partials, then 'pre')
    u16* Qp   = (u16*)(ws + 60456960);                   // 57,802,752
    u16* Kp   = (u16*)(ws + 118259712);                  // 57,802,752
    u16* Vp   = (u16*)(ws + 176062464);                  // 57,802,752
    float* af = (float*)(ws + 233865216);                //  1,806,336
    u16* px   = (u16*)(ws + 235671552);                  //    903,168 (agv region: disjoint lifetime)
    float* agv= (float*)(ws + 235671552);                //  1,806,336
    float* b1 = (float*)(ws + 237477888);                //  4,917,248  [h][n][49]
    float* b2p= (float*)(ws + 242395136);                //  6,422,528  [h][n][64] padded
    float* part = (float*)xb;                            // 11,139,072 (inside xb region; dead before 'pre')

    k_cast_x<<<28224, 256, 0, stream>>>(x, xb);
    k_prep_w<<<5184, 256, 0, stream>>>(Wq, Wkv, projw, wbT, wpT);
    k_bias1<<<4802, 256, 0, stream>>>(an_b, ah_b, aw_b, b1);
    k_bias2<<<6272, 256, 0, stream>>>(na_b, ha_b, wa_b, b2p);
    k_poolx<<<112, 256, 0, stream>>>(xb, px);
    k_gemm<2><<<dim3(5, 7), 256, 0, stream>>>(px, wbT, nullptr, nullptr, nullptr, af, nullptr, 784);
    k_gemm<0><<<dim3(14, 392), 256, 0, stream>>>(xb, wbT, Qp, Kp, Vp, nullptr, nullptr, BB * NN);
    k_stageA<<<dim3(NCH, 128), 256, 0, stream>>>(Kp, Vp, af, b1, part);
    k_reduceA<<<128, 256, 0, stream>>>(part, agv);
    k_stageBC<<<dim3(13, 128), 256, 0, stream>>>(Qp, af, agv, b2p, Vp, dwcw, gam, bet, xb /*pre*/);
    k_gemm<1><<<dim3(5, 392), 256, 0, stream>>>(xb /*pre*/, wpT, nullptr, nullptr, nullptr, out, projb, BB * NN);
}